// Round 11
// baseline (326.056 us; speedup 1.0000x reference)
//
#include <hip/hip_runtime.h>
#include <hip/hip_bf16.h>
#include <math.h>

#ifndef __has_builtin
#define __has_builtin(x) 0
#endif
#if __has_builtin(__builtin_amdgcn_cvt_pk_fp8_f32) && __has_builtin(__builtin_amdgcn_cvt_pk_f32_fp8)
#define FP8_HW 1
#else
#include <hip/hip_fp8.h>
#endif

#define D 128
#define KVREC 384   // 128 B k (fp8 e4m3) + 256 B v (bf16)

typedef float f32x16 __attribute__((ext_vector_type(16)));
typedef float f32x2  __attribute__((ext_vector_type(2)));
typedef short bf16x8 __attribute__((ext_vector_type(8)));

// gelu tanh-approx, exact rewrite: 0.5x(1+tanh(u)) == x / (1 + e^{-2u})
__device__ __forceinline__ float gelu_fast(float x) {
    float u = 0.7978845608028654f * (x + 0.044715f * x * x * x);
    return x / (1.0f + __expf(-2.0f * u));
}

__device__ __forceinline__ unsigned short f2bf(float f) {
    union { float f; unsigned u; } x; x.f = f;
    unsigned r = x.u + 0x7fff + ((x.u >> 16) & 1);   // RNE
    return (unsigned short)(r >> 16);
}

__device__ __forceinline__ float bflo(unsigned u) { return __uint_as_float(u << 16); }
__device__ __forceinline__ float bfhi(unsigned u) { return __uint_as_float(u & 0xffff0000u); }

__device__ __forceinline__ unsigned char f2fp8(float x) {
#ifdef FP8_HW
    return (unsigned char)(__builtin_amdgcn_cvt_pk_fp8_f32(x, x, 0, false) & 0xFF);
#else
    __hip_fp8_e4m3 h(x); return (unsigned char)h.__x;
#endif
}

__device__ __forceinline__ void fp8x4d(unsigned u, float* f) {
#ifdef FP8_HW
    f32x2 lo = __builtin_amdgcn_cvt_pk_f32_fp8((int)u, false);
    f32x2 hi = __builtin_amdgcn_cvt_pk_f32_fp8((int)u, true);
    f[0] = lo[0]; f[1] = lo[1]; f[2] = hi[0]; f[3] = hi[1];
#else
    #pragma unroll
    for (int i = 0; i < 4; ++i) {
        __hip_fp8_e4m3 h; h.__x = (unsigned char)((u >> (8 * i)) & 0xFF);
        f[i] = (float)h;
    }
#endif
}

// ================= fused_pre: hist (blocks < nbE8) || prepack (last 192) =====

__global__ __launch_bounds__(256) void fused_pre_kernel(
    const int* __restrict__ rows, int* __restrict__ cnt, int nE, int n, int nbE8,
    const float* __restrict__ W0, const float* __restrict__ W1,
    const float* __restrict__ W2, unsigned short* __restrict__ F)
{
    const int bid = blockIdx.x;
    if (bid < nbE8) {
        // ---- hist: XCD-sliced (group g = bid&7 owns rows [g*n/8,(g+1)*n/8)) ----
        const int g  = bid & 7;
        const int lo = (int)(((long long)g * n) >> 3);
        const int hi = (int)(((long long)(g + 1) * n) >> 3);
        const int idx = (bid >> 3) * 1024 + threadIdx.x * 4;
        if (idx + 3 < nE) {
            int4 r4 = *reinterpret_cast<const int4*>(rows + idx);
            if (r4.x >= lo && r4.x < hi) atomicAdd(&cnt[r4.x], 1);
            if (r4.y >= lo && r4.y < hi) atomicAdd(&cnt[r4.y], 1);
            if (r4.z >= lo && r4.z < hi) atomicAdd(&cnt[r4.z], 1);
            if (r4.w >= lo && r4.w < hi) atomicAdd(&cnt[r4.w], 1);
        } else {
            for (int i = 0; i < 4; ++i)
                if (idx + i < nE) {
                    int r = rows[idx + i];
                    if (r >= lo && r < hi) atomicAdd(&cnt[r], 1);
                }
        }
    } else {
        // ---- prepack: 3 W[128][128] -> MFMA B-fragment order (bf16) ----
        int gidx = (bid - nbE8) * 256 + threadIdx.x;
        if (gidx >= 3 * 32 * 64 * 8) return;
        const int midx = gidx >> 14;
        const int idx  = gidx & 16383;
        const float* W = midx == 0 ? W0 : (midx == 1 ? W1 : W2);
        int j  = idx & 7;
        int l  = (idx >> 3) & 63;
        int kt = (idx >> 9) & 7;
        int ct = idx >> 12;
        int kk = kt * 16 + (l >> 5) * 8 + j;
        int c  = ct * 32 + (l & 31);
        F[gidx] = f2bf(W[kk * D + c]);
    }
}

// ================= scan: block sums, then write (with inline boff re-scan) ===

__global__ __launch_bounds__(256) void scan_bsum_kernel(
    const int* __restrict__ cnt, int* __restrict__ bsum, int n)
{
    __shared__ int s[256];
    const int t = threadIdx.x;
    const int base = blockIdx.x * 1024 + t * 4;
    int sum = 0;
    if (base + 3 < n) {
        int4 c4 = *reinterpret_cast<const int4*>(cnt + base);
        sum = c4.x + c4.y + c4.z + c4.w;
    } else {
        for (int i = 0; i < 4; ++i) if (base + i < n) sum += cnt[base + i];
    }
    s[t] = sum;
    __syncthreads();
    #pragma unroll
    for (int off = 128; off > 0; off >>= 1) {
        if (t < off) s[t] += s[t + off];
        __syncthreads();
    }
    if (t == 0) bsum[blockIdx.x] = s[0];
}

// Each block re-scans bsum[0..nb) in LDS, then writes rowptr AND cur.
__global__ __launch_bounds__(256) void scan_write2_kernel(
    const int* __restrict__ cnt, const int* __restrict__ bsum, int nb,
    int* __restrict__ rowptr, int* __restrict__ cur, int n)
{
    __shared__ int s[256];
    const int t = threadIdx.x;

    // phase A: inclusive scan of block sums
    s[t] = (t < nb) ? bsum[t] : 0;
    __syncthreads();
    #pragma unroll
    for (int off = 1; off < 256; off <<= 1) {
        int v = (t >= off) ? s[t - off] : 0;
        __syncthreads();
        s[t] += v;
        __syncthreads();
    }
    const int boffv = (blockIdx.x > 0) ? s[blockIdx.x - 1] : 0;  // exclusive
    const int total = s[255];
    if (blockIdx.x == 0 && t == 0) rowptr[n] = total;
    __syncthreads();   // everyone has boffv; safe to reuse s

    // phase B: per-1024-chunk scan
    const int base = blockIdx.x * 1024 + t * 4;
    int c[4] = {0, 0, 0, 0};
    if (base + 3 < n) {
        int4 c4 = *reinterpret_cast<const int4*>(cnt + base);
        c[0] = c4.x; c[1] = c4.y; c[2] = c4.z; c[3] = c4.w;
    } else {
        for (int i = 0; i < 4; ++i) if (base + i < n) c[i] = cnt[base + i];
    }
    const int tsum = c[0] + c[1] + c[2] + c[3];
    s[t] = tsum;
    __syncthreads();
    #pragma unroll
    for (int off = 1; off < 256; off <<= 1) {
        int v = (t >= off) ? s[t - off] : 0;
        __syncthreads();
        s[t] += v;
        __syncthreads();
    }
    int run = boffv + s[t] - tsum;
    int w0 = run;
    int w1 = run + c[0];
    int w2 = w1 + c[1];
    int w3 = w2 + c[2];
    if (base + 3 < n) {
        int4 wv = make_int4(w0, w1, w2, w3);
        *reinterpret_cast<int4*>(rowptr + base) = wv;
        *reinterpret_cast<int4*>(cur + base)    = wv;
    } else {
        int w[4] = {w0, w1, w2, w3};
        for (int i = 0; i < 4; ++i)
            if (base + i < n) { rowptr[base + i] = w[i]; cur[base + i] = w[i]; }
    }
}

// ================= scatter: standalone, low-VGPR, ILP-batched atomics ========
// 8 edges/thread; all 8 atomicAdds issued before any dependent store.

__global__ __launch_bounds__(256, 8) void scatter_kernel(
    const int* __restrict__ rows, const int* __restrict__ cols,
    int* __restrict__ cur, int* __restrict__ colsorted, int nE, int n)
{
    const int g  = blockIdx.x & 7;
    const int lo = (int)(((long long)g * n) >> 3);
    const int hi = (int)(((long long)(g + 1) * n) >> 3);
    const int idx = (blockIdx.x >> 3) * 2048 + threadIdx.x * 8;
    if (idx + 7 < nE) {
        int4 ra = *reinterpret_cast<const int4*>(rows + idx);
        int4 rb = *reinterpret_cast<const int4*>(rows + idx + 4);
        int4 ca = *reinterpret_cast<const int4*>(cols + idx);
        int4 cb = *reinterpret_cast<const int4*>(cols + idx + 4);
        int r[8] = {ra.x, ra.y, ra.z, ra.w, rb.x, rb.y, rb.z, rb.w};
        int c[8] = {ca.x, ca.y, ca.z, ca.w, cb.x, cb.y, cb.z, cb.w};
        int p[8];
        #pragma unroll
        for (int j = 0; j < 8; ++j)
            p[j] = (r[j] >= lo && r[j] < hi) ? atomicAdd(&cur[r[j]], 1) : -1;
        #pragma unroll
        for (int j = 0; j < 8; ++j)
            if (p[j] >= 0) colsorted[p[j]] = c[j];
    } else {
        for (int i = 0; i < 8; ++i)
            if (idx + i < nE) {
                int r = rows[idx + i];
                if (r >= lo && r < hi)
                    colsorted[atomicAdd(&cur[r], 1)] = cols[idx + i];
            }
    }
}

// ================= proj: q (blocks < nbQ) || kv (rest), LDS-staged A =========
// R11: reverted to R8's LDS staging (R9/R10's direct-global A-fragment loads
// are 64-distinct-cachelines-per-instruction divergent -> proj stuck at 97us;
// coalesced float4 staging is 16 contiguous lines per instruction).

__global__ __launch_bounds__(256) void proj_kernel(
    const float* __restrict__ Xq, const float* __restrict__ Xm,
    const unsigned short* __restrict__ Fq, const float* __restrict__ bq,
    unsigned short* __restrict__ qout,
    const unsigned short* __restrict__ Fk, const float* __restrict__ bk,
    const unsigned short* __restrict__ Fv, const float* __restrict__ bv,
    unsigned char* __restrict__ kv,
    int n, int m, int nbQ)
{
    __shared__ __align__(16) unsigned short sX[128][136];
    const int bid = blockIdx.x;
    const int tid = threadIdx.x;

    const bool isQ = bid < nbQ;
    const int row0 = (isQ ? bid : bid - nbQ) * 128;
    const int nn   = isQ ? n : m;
    const float* X = isQ ? Xq : Xm;

    // stage 128x128 f32 -> bf16 LDS, coalesced float4 reads
    #pragma unroll
    for (int p = 0; p < 16; ++p) {
        int flat = p * 256 + tid;
        int r = flat >> 5;
        int c = (flat & 31) * 4;
        int gr = row0 + r; if (gr >= nn) gr = nn - 1;   // clamp; stores guarded
        float4 x4 = *reinterpret_cast<const float4*>(X + (size_t)gr * D + c);
        uint2 pk;
        pk.x = (unsigned)f2bf(x4.x) | ((unsigned)f2bf(x4.y) << 16);
        pk.y = (unsigned)f2bf(x4.z) | ((unsigned)f2bf(x4.w) << 16);
        *reinterpret_cast<uint2*>(&sX[r][c]) = pk;
    }
    __syncthreads();

    const int l = tid & 63;
    const int w = tid >> 6;
    const int arow = w * 32 + (l & 31);

    bf16x8 af[8];
    #pragma unroll
    for (int kt = 0; kt < 8; ++kt)
        af[kt] = *reinterpret_cast<const bf16x8*>(&sX[arow][kt * 16 + (l >> 5) * 8]);

    if (isQ) {
        #pragma unroll
        for (int ct = 0; ct < 4; ++ct) {
            f32x16 acc = {};
            #pragma unroll
            for (int kt = 0; kt < 8; ++kt) {
                bf16x8 bfr = *reinterpret_cast<const bf16x8*>(Fq + ((size_t)((ct * 8 + kt) * 64 + l) * 8));
                acc = __builtin_amdgcn_mfma_f32_32x32x16_bf16(af[kt], bfr, acc, 0, 0, 0);
            }
            const int col = ct * 32 + (l & 31);
            const float bb = bq[col];
            #pragma unroll
            for (int reg = 0; reg < 16; ++reg) {
                int r  = (reg & 3) + 8 * (reg >> 2) + 4 * (l >> 5);
                int gr = row0 + w * 32 + r;
                if (gr < nn)
                    qout[(size_t)gr * D + col] = f2bf(gelu_fast(acc[reg] + bb));
            }
        }
    } else {
        for (int mat = 0; mat < 2; ++mat) {
            const unsigned short* F = mat ? Fv : Fk;
            const float* bias       = mat ? bv : bk;
            #pragma unroll
            for (int ct = 0; ct < 4; ++ct) {
                f32x16 acc = {};
                #pragma unroll
                for (int kt = 0; kt < 8; ++kt) {
                    bf16x8 bfr = *reinterpret_cast<const bf16x8*>(F + ((size_t)((ct * 8 + kt) * 64 + l) * 8));
                    acc = __builtin_amdgcn_mfma_f32_32x32x16_bf16(af[kt], bfr, acc, 0, 0, 0);
                }
                const int col = ct * 32 + (l & 31);
                const float bb = bias[col];
                #pragma unroll
                for (int reg = 0; reg < 16; ++reg) {
                    int r  = (reg & 3) + 8 * (reg >> 2) + 4 * (l >> 5);
                    int gr = row0 + w * 32 + r;
                    if (gr < nn) {
                        unsigned char* rec = kv + (size_t)gr * KVREC;
                        float val = gelu_fast(acc[reg] + bb);
                        if (mat == 0)
                            rec[col] = f2fp8(val);
                        else
                            reinterpret_cast<unsigned short*>(rec + 128)[col] = f2bf(val);
                    }
                }
            }
        }
    }
}

// ---- aggregation: one wave per row, 4 edges in flight (16 lanes each) ----
// q bf16 [n][128]; kv record [m][384]: k fp8 (128 B) then v bf16 (256 B)
__global__ __launch_bounds__(256) void agg_kernel(
    const unsigned short* __restrict__ q, const unsigned char* __restrict__ kv,
    const int* __restrict__ rowptr, const int* __restrict__ colsorted,
    float* __restrict__ out, int n)
{
    const int wave = (blockIdx.x * 256 + threadIdx.x) >> 6;
    if (wave >= n) return;
    const int lane = threadIdx.x & 63;
    const int sub  = lane >> 4;
    const int l    = lane & 15;

    const uint4 qa = *reinterpret_cast<const uint4*>(q + (size_t)wave * D + l * 8);
    float qf[8];
    qf[0] = bflo(qa.x); qf[1] = bfhi(qa.x);
    qf[2] = bflo(qa.y); qf[3] = bfhi(qa.y);
    qf[4] = bflo(qa.z); qf[5] = bfhi(qa.z);
    qf[6] = bflo(qa.w); qf[7] = bfhi(qa.w);

    float acc[8] = {0.f,0.f,0.f,0.f,0.f,0.f,0.f,0.f};
    const int start = rowptr[wave], end = rowptr[wave + 1];

    #pragma unroll 2
    for (int i = start + sub; i < end; i += 4) {
        const int c = colsorted[i];
        const unsigned char* rec = kv + (size_t)c * KVREC;
        const uint2 kb = *reinterpret_cast<const uint2*>(rec + l * 8);
        const uint4 vb = *reinterpret_cast<const uint4*>(rec + 128 + l * 16);

        float kf[8];
        fp8x4d(kb.x, kf); fp8x4d(kb.y, kf + 4);

        float dot = 0.0f;
        #pragma unroll
        for (int j = 0; j < 8; ++j) dot = fmaf(qf[j], kf[j], dot);
        dot += __shfl_xor(dot, 1);
        dot += __shfl_xor(dot, 2);
        dot += __shfl_xor(dot, 4);
        dot += __shfl_xor(dot, 8);
        const float coef = 1.0f / (1.0f + __expf(-dot * 0.08838834764831845f));

        acc[0] = fmaf(coef, bflo(vb.x), acc[0]);
        acc[1] = fmaf(coef, bfhi(vb.x), acc[1]);
        acc[2] = fmaf(coef, bflo(vb.y), acc[2]);
        acc[3] = fmaf(coef, bfhi(vb.y), acc[3]);
        acc[4] = fmaf(coef, bflo(vb.z), acc[4]);
        acc[5] = fmaf(coef, bfhi(vb.z), acc[5]);
        acc[6] = fmaf(coef, bflo(vb.w), acc[6]);
        acc[7] = fmaf(coef, bfhi(vb.w), acc[7]);
    }

    #pragma unroll
    for (int j = 0; j < 8; ++j) {
        acc[j] += __shfl_xor(acc[j], 16);
        acc[j] += __shfl_xor(acc[j], 32);
    }

    if (sub == 0) {
        float* op = out + (size_t)wave * D + l * 8;
        float4 o0 = {acc[0], acc[1], acc[2], acc[3]};
        float4 o1 = {acc[4], acc[5], acc[6], acc[7]};
        *reinterpret_cast<float4*>(op)     = o0;
        *reinterpret_cast<float4*>(op + 4) = o1;
    }
}

extern "C" void kernel_launch(void* const* d_in, const int* in_sizes, int n_in,
                              void* d_out, int out_size, void* d_ws, size_t ws_size,
                              hipStream_t stream) {
    const float* query  = (const float*)d_in[0];
    const float* memory = (const float*)d_in[1];
    const float* Wq     = (const float*)d_in[2];
    const float* bq     = (const float*)d_in[3];
    const float* Wk     = (const float*)d_in[4];
    const float* bk     = (const float*)d_in[5];
    const float* Wv     = (const float*)d_in[6];
    const float* bv     = (const float*)d_in[7];
    const int*   erows  = (const int*)d_in[8];
    const int*   ecols  = (const int*)d_in[9];

    const int n  = in_sizes[0] / D;   // 100000
    const int m  = in_sizes[1] / D;   // 100000
    const int nE = in_sizes[8];       // 1600000

    char* base = (char*)d_ws;
    size_t off = 0;
    auto carve = [&](size_t bytes) -> char* {
        char* p = base + off;
        off = (off + bytes + 255) & ~(size_t)255;
        return p;
    };
    unsigned short* q   = (unsigned short*)carve((size_t)n * D * sizeof(unsigned short));
    unsigned char*  kv  = (unsigned char*) carve((size_t)m * KVREC);
    unsigned short* F   = (unsigned short*)carve(3 * 32 * 64 * 8 * sizeof(unsigned short));
    int*   rowptr    = (int*)carve((size_t)(n + 1) * sizeof(int));
    int*   cnt       = (int*)carve((size_t)(n + 1) * sizeof(int));
    int*   cur       = (int*)carve((size_t)(n + 1) * sizeof(int));
    int*   bsum      = (int*)carve(256 * sizeof(int));
    int*   colsorted = (int*)carve((size_t)nE * sizeof(int));
    float* out       = (float*)d_out;

    unsigned short* Fq = F;
    unsigned short* Fk = F + 16384;
    unsigned short* Fv = F + 32768;

    dim3 blk(256);
    const int nbScan = (n + 1023) / 1024;            // 98 <= 256
    const int nbE8   = ((nE + 1023) / 1024) * 8;     // hist blocks (4 edges/thr)
    const int nbSc   = ((nE + 2047) / 2048) * 8;     // scatter blocks (8 edges/thr)
    const int nbQ    = (n + 127) / 128;
    const int nbM    = (m + 127) / 128;

    // 1) zero counters
    hipMemsetAsync(cnt, 0, (size_t)(n + 1) * sizeof(int), stream);
    // 2) hist || prepack
    fused_pre_kernel<<<dim3(nbE8 + 192), blk, 0, stream>>>(
        erows, cnt, nE, n, nbE8, Wq, Wk, Wv, F);
    // 3) block sums
    scan_bsum_kernel<<<dim3(nbScan), blk, 0, stream>>>(cnt, bsum, n);
    // 4) rowptr + cur (inline boff re-scan)
    scan_write2_kernel<<<dim3(nbScan), blk, 0, stream>>>(cnt, bsum, nbScan, rowptr, cur, n);
    // 5) scatter (standalone: low VGPR, 8 waves/SIMD, ILP-batched atomics)
    scatter_kernel<<<dim3(nbSc), blk, 0, stream>>>(erows, ecols, cur, colsorted, nE, n);
    // 6) projections q || kv (LDS-staged A-tiles)
    proj_kernel<<<dim3(nbQ + nbM), blk, 0, stream>>>(
        query, memory, Fq, bq, q, Fk, bk, Fv, bv, kv, n, m, nbQ);
    // 7) aggregation (writes all outputs; no out memset needed)
    agg_kernel<<<dim3((n * 64 + 255) / 256), blk, 0, stream>>>(q, kv, rowptr, colsorted, out, n);
}

// Round 12
// 290.467 us; speedup vs baseline: 1.1225x; 1.1225x over previous
//
#include <hip/hip_runtime.h>
#include <hip/hip_bf16.h>
#include <math.h>

#ifndef __has_builtin
#define __has_builtin(x) 0
#endif
#if __has_builtin(__builtin_amdgcn_cvt_pk_fp8_f32) && __has_builtin(__builtin_amdgcn_cvt_pk_f32_fp8)
#define FP8_HW 1
#else
#include <hip/hip_fp8.h>
#endif

#define D 128
#define KVREC 384   // 128 B k (fp8 e4m3) + 256 B v (bf16)

typedef float f32x16 __attribute__((ext_vector_type(16)));
typedef float f32x2  __attribute__((ext_vector_type(2)));
typedef short bf16x8 __attribute__((ext_vector_type(8)));

// gelu tanh-approx, exact rewrite: 0.5x(1+tanh(u)) == x / (1 + e^{-2u})
__device__ __forceinline__ float gelu_fast(float x) {
    float u = 0.7978845608028654f * (x + 0.044715f * x * x * x);
    return x / (1.0f + __expf(-2.0f * u));
}

__device__ __forceinline__ unsigned short f2bf(float f) {
    union { float f; unsigned u; } x; x.f = f;
    unsigned r = x.u + 0x7fff + ((x.u >> 16) & 1);   // RNE
    return (unsigned short)(r >> 16);
}

__device__ __forceinline__ float bflo(unsigned u) { return __uint_as_float(u << 16); }
__device__ __forceinline__ float bfhi(unsigned u) { return __uint_as_float(u & 0xffff0000u); }

__device__ __forceinline__ unsigned char f2fp8(float x) {
#ifdef FP8_HW
    return (unsigned char)(__builtin_amdgcn_cvt_pk_fp8_f32(x, x, 0, false) & 0xFF);
#else
    __hip_fp8_e4m3 h(x); return (unsigned char)h.__x;
#endif
}

__device__ __forceinline__ void fp8x4d(unsigned u, float* f) {
#ifdef FP8_HW
    f32x2 lo = __builtin_amdgcn_cvt_pk_f32_fp8((int)u, false);
    f32x2 hi = __builtin_amdgcn_cvt_pk_f32_fp8((int)u, true);
    f[0] = lo[0]; f[1] = lo[1]; f[2] = hi[0]; f[3] = hi[1];
#else
    #pragma unroll
    for (int i = 0; i < 4; ++i) {
        __hip_fp8_e4m3 h; h.__x = (unsigned char)((u >> (8 * i)) & 0xFF);
        f[i] = (float)h;
    }
#endif
}

// ================= fused_pre: hist+rank (blocks < nbE8) || prepack ==========
// hist stores the atomicAdd RETURN VALUE as the edge's within-row rank.
// This is what scatter's atomic used to recompute -> scatter goes atomic-free.

__global__ __launch_bounds__(256) void fused_pre_kernel(
    const int* __restrict__ rows, int* __restrict__ cnt, int* __restrict__ rank,
    int nE, int n, int nbE8,
    const float* __restrict__ W0, const float* __restrict__ W1,
    const float* __restrict__ W2, unsigned short* __restrict__ F)
{
    const int bid = blockIdx.x;
    if (bid < nbE8) {
        // ---- hist: XCD-sliced (group g = bid&7 owns rows [g*n/8,(g+1)*n/8)) ----
        const int g  = bid & 7;
        const int lo = (int)(((long long)g * n) >> 3);
        const int hi = (int)(((long long)(g + 1) * n) >> 3);
        const int idx = (bid >> 3) * 1024 + threadIdx.x * 4;
        if (idx + 3 < nE) {
            int4 r4 = *reinterpret_cast<const int4*>(rows + idx);
            int rk[4] = {-1, -1, -1, -1};
            if (r4.x >= lo && r4.x < hi) rk[0] = atomicAdd(&cnt[r4.x], 1);
            if (r4.y >= lo && r4.y < hi) rk[1] = atomicAdd(&cnt[r4.y], 1);
            if (r4.z >= lo && r4.z < hi) rk[2] = atomicAdd(&cnt[r4.z], 1);
            if (r4.w >= lo && r4.w < hi) rk[3] = atomicAdd(&cnt[r4.w], 1);
            #pragma unroll
            for (int j = 0; j < 4; ++j)
                if (rk[j] >= 0) rank[idx + j] = rk[j];
        } else {
            for (int i = 0; i < 4; ++i)
                if (idx + i < nE) {
                    int r = rows[idx + i];
                    if (r >= lo && r < hi) rank[idx + i] = atomicAdd(&cnt[r], 1);
                }
        }
    } else {
        // ---- prepack: 3 W[128][128] -> MFMA B-fragment order (bf16) ----
        int gidx = (bid - nbE8) * 256 + threadIdx.x;
        if (gidx >= 3 * 32 * 64 * 8) return;
        const int midx = gidx >> 14;
        const int idx  = gidx & 16383;
        const float* W = midx == 0 ? W0 : (midx == 1 ? W1 : W2);
        int j  = idx & 7;
        int l  = (idx >> 3) & 63;
        int kt = (idx >> 9) & 7;
        int ct = idx >> 12;
        int kk = kt * 16 + (l >> 5) * 8 + j;
        int c  = ct * 32 + (l & 31);
        F[gidx] = f2bf(W[kk * D + c]);
    }
}

// ================= scan: block sums, then write (with inline boff re-scan) ===

__global__ __launch_bounds__(256) void scan_bsum_kernel(
    const int* __restrict__ cnt, int* __restrict__ bsum, int n)
{
    __shared__ int s[256];
    const int t = threadIdx.x;
    const int base = blockIdx.x * 1024 + t * 4;
    int sum = 0;
    if (base + 3 < n) {
        int4 c4 = *reinterpret_cast<const int4*>(cnt + base);
        sum = c4.x + c4.y + c4.z + c4.w;
    } else {
        for (int i = 0; i < 4; ++i) if (base + i < n) sum += cnt[base + i];
    }
    s[t] = sum;
    __syncthreads();
    #pragma unroll
    for (int off = 128; off > 0; off >>= 1) {
        if (t < off) s[t] += s[t + off];
        __syncthreads();
    }
    if (t == 0) bsum[blockIdx.x] = s[0];
}

// Each block re-scans bsum[0..nb) in LDS, then writes rowptr.
__global__ __launch_bounds__(256) void scan_write2_kernel(
    const int* __restrict__ cnt, const int* __restrict__ bsum, int nb,
    int* __restrict__ rowptr, int n)
{
    __shared__ int s[256];
    const int t = threadIdx.x;

    // phase A: inclusive scan of block sums
    s[t] = (t < nb) ? bsum[t] : 0;
    __syncthreads();
    #pragma unroll
    for (int off = 1; off < 256; off <<= 1) {
        int v = (t >= off) ? s[t - off] : 0;
        __syncthreads();
        s[t] += v;
        __syncthreads();
    }
    const int boffv = (blockIdx.x > 0) ? s[blockIdx.x - 1] : 0;  // exclusive
    const int total = s[255];
    if (blockIdx.x == 0 && t == 0) rowptr[n] = total;
    __syncthreads();   // everyone has boffv; safe to reuse s

    // phase B: per-1024-chunk scan
    const int base = blockIdx.x * 1024 + t * 4;
    int c[4] = {0, 0, 0, 0};
    if (base + 3 < n) {
        int4 c4 = *reinterpret_cast<const int4*>(cnt + base);
        c[0] = c4.x; c[1] = c4.y; c[2] = c4.z; c[3] = c4.w;
    } else {
        for (int i = 0; i < 4; ++i) if (base + i < n) c[i] = cnt[base + i];
    }
    const int tsum = c[0] + c[1] + c[2] + c[3];
    s[t] = tsum;
    __syncthreads();
    #pragma unroll
    for (int off = 1; off < 256; off <<= 1) {
        int v = (t >= off) ? s[t - off] : 0;
        __syncthreads();
        s[t] += v;
        __syncthreads();
    }
    int run = boffv + s[t] - tsum;
    int w0 = run;
    int w1 = run + c[0];
    int w2 = w1 + c[1];
    int w3 = w2 + c[2];
    if (base + 3 < n) {
        *reinterpret_cast<int4*>(rowptr + base) = make_int4(w0, w1, w2, w3);
    } else {
        int w[4] = {w0, w1, w2, w3};
        for (int i = 0; i < 4; ++i) if (base + i < n) rowptr[base + i] = w[i];
    }
}

// ================= scatter: rank-based, ATOMIC-FREE streaming ================
// pos = rowptr[r] + rank[e]; pure {coalesced reads, one L2-hot gather, store}.

__global__ __launch_bounds__(256, 8) void scatter_kernel(
    const int* __restrict__ rows, const int* __restrict__ cols,
    const int* __restrict__ rank, const int* __restrict__ rowptr,
    int* __restrict__ colsorted, int nE, int n)
{
    const int g  = blockIdx.x & 7;
    const int lo = (int)(((long long)g * n) >> 3);
    const int hi = (int)(((long long)(g + 1) * n) >> 3);
    const int idx = (blockIdx.x >> 3) * 2048 + threadIdx.x * 8;
    if (idx + 7 < nE) {
        int4 ra = *reinterpret_cast<const int4*>(rows + idx);
        int4 rb = *reinterpret_cast<const int4*>(rows + idx + 4);
        int4 ca = *reinterpret_cast<const int4*>(cols + idx);
        int4 cb = *reinterpret_cast<const int4*>(cols + idx + 4);
        int4 ka = *reinterpret_cast<const int4*>(rank + idx);
        int4 kb = *reinterpret_cast<const int4*>(rank + idx + 4);
        int r[8] = {ra.x, ra.y, ra.z, ra.w, rb.x, rb.y, rb.z, rb.w};
        int c[8] = {ca.x, ca.y, ca.z, ca.w, cb.x, cb.y, cb.z, cb.w};
        int k[8] = {ka.x, ka.y, ka.z, ka.w, kb.x, kb.y, kb.z, kb.w};
        int p[8];
        #pragma unroll
        for (int j = 0; j < 8; ++j)
            p[j] = (r[j] >= lo && r[j] < hi) ? rowptr[r[j]] + k[j] : -1;
        #pragma unroll
        for (int j = 0; j < 8; ++j)
            if (p[j] >= 0) colsorted[p[j]] = c[j];
    } else {
        for (int i = 0; i < 8; ++i)
            if (idx + i < nE) {
                int r = rows[idx + i];
                if (r >= lo && r < hi)
                    colsorted[rowptr[r] + rank[idx + i]] = cols[idx + i];
            }
    }
}

// ================= proj: q (blocks < nbQ) || kv (rest), LDS-staged A =========

__global__ __launch_bounds__(256) void proj_kernel(
    const float* __restrict__ Xq, const float* __restrict__ Xm,
    const unsigned short* __restrict__ Fq, const float* __restrict__ bq,
    unsigned short* __restrict__ qout,
    const unsigned short* __restrict__ Fk, const float* __restrict__ bk,
    const unsigned short* __restrict__ Fv, const float* __restrict__ bv,
    unsigned char* __restrict__ kv,
    int n, int m, int nbQ)
{
    __shared__ __align__(16) unsigned short sX[128][136];
    const int bid = blockIdx.x;
    const int tid = threadIdx.x;

    const bool isQ = bid < nbQ;
    const int row0 = (isQ ? bid : bid - nbQ) * 128;
    const int nn   = isQ ? n : m;
    const float* X = isQ ? Xq : Xm;

    // stage 128x128 f32 -> bf16 LDS, coalesced float4 reads
    #pragma unroll
    for (int p = 0; p < 16; ++p) {
        int flat = p * 256 + tid;
        int r = flat >> 5;
        int c = (flat & 31) * 4;
        int gr = row0 + r; if (gr >= nn) gr = nn - 1;   // clamp; stores guarded
        float4 x4 = *reinterpret_cast<const float4*>(X + (size_t)gr * D + c);
        uint2 pk;
        pk.x = (unsigned)f2bf(x4.x) | ((unsigned)f2bf(x4.y) << 16);
        pk.y = (unsigned)f2bf(x4.z) | ((unsigned)f2bf(x4.w) << 16);
        *reinterpret_cast<uint2*>(&sX[r][c]) = pk;
    }
    __syncthreads();

    const int l = tid & 63;
    const int w = tid >> 6;
    const int arow = w * 32 + (l & 31);

    bf16x8 af[8];
    #pragma unroll
    for (int kt = 0; kt < 8; ++kt)
        af[kt] = *reinterpret_cast<const bf16x8*>(&sX[arow][kt * 16 + (l >> 5) * 8]);

    if (isQ) {
        #pragma unroll
        for (int ct = 0; ct < 4; ++ct) {
            f32x16 acc = {};
            #pragma unroll
            for (int kt = 0; kt < 8; ++kt) {
                bf16x8 bfr = *reinterpret_cast<const bf16x8*>(Fq + ((size_t)((ct * 8 + kt) * 64 + l) * 8));
                acc = __builtin_amdgcn_mfma_f32_32x32x16_bf16(af[kt], bfr, acc, 0, 0, 0);
            }
            const int col = ct * 32 + (l & 31);
            const float bb = bq[col];
            #pragma unroll
            for (int reg = 0; reg < 16; ++reg) {
                int r  = (reg & 3) + 8 * (reg >> 2) + 4 * (l >> 5);
                int gr = row0 + w * 32 + r;
                if (gr < nn)
                    qout[(size_t)gr * D + col] = f2bf(gelu_fast(acc[reg] + bb));
            }
        }
    } else {
        for (int mat = 0; mat < 2; ++mat) {
            const unsigned short* F = mat ? Fv : Fk;
            const float* bias       = mat ? bv : bk;
            #pragma unroll
            for (int ct = 0; ct < 4; ++ct) {
                f32x16 acc = {};
                #pragma unroll
                for (int kt = 0; kt < 8; ++kt) {
                    bf16x8 bfr = *reinterpret_cast<const bf16x8*>(F + ((size_t)((ct * 8 + kt) * 64 + l) * 8));
                    acc = __builtin_amdgcn_mfma_f32_32x32x16_bf16(af[kt], bfr, acc, 0, 0, 0);
                }
                const int col = ct * 32 + (l & 31);
                const float bb = bias[col];
                #pragma unroll
                for (int reg = 0; reg < 16; ++reg) {
                    int r  = (reg & 3) + 8 * (reg >> 2) + 4 * (l >> 5);
                    int gr = row0 + w * 32 + r;
                    if (gr < nn) {
                        unsigned char* rec = kv + (size_t)gr * KVREC;
                        float val = gelu_fast(acc[reg] + bb);
                        if (mat == 0)
                            rec[col] = f2fp8(val);
                        else
                            reinterpret_cast<unsigned short*>(rec + 128)[col] = f2bf(val);
                    }
                }
            }
        }
    }
}

// ================= aggregation: 8-lane edge groups, 8 edges in flight ========
// Wave = 1 row. Lane: sub = lane>>3 (edge slot 0..7), s = lane&7 (dims s*16..+15).
// Bigger per-lane loads (k: 1 uint4, v: 2 uint4), 3-level dot shuffle.

__global__ __launch_bounds__(256) void agg_kernel(
    const unsigned short* __restrict__ q, const unsigned char* __restrict__ kv,
    const int* __restrict__ rowptr, const int* __restrict__ colsorted,
    float* __restrict__ out, int n)
{
    const int wave = (blockIdx.x * 256 + threadIdx.x) >> 6;
    if (wave >= n) return;
    const int lane = threadIdx.x & 63;
    const int sub  = lane >> 3;     // edge slot 0..7
    const int s    = lane & 7;      // dims s*16 .. s*16+15

    const uint4 qa = *reinterpret_cast<const uint4*>(q + (size_t)wave * D + s * 16);
    const uint4 qb = *reinterpret_cast<const uint4*>(q + (size_t)wave * D + s * 16 + 8);
    float qf[16];
    qf[0] = bflo(qa.x); qf[1] = bfhi(qa.x); qf[2]  = bflo(qa.y); qf[3]  = bfhi(qa.y);
    qf[4] = bflo(qa.z); qf[5] = bfhi(qa.z); qf[6]  = bflo(qa.w); qf[7]  = bfhi(qa.w);
    qf[8] = bflo(qb.x); qf[9] = bfhi(qb.x); qf[10] = bflo(qb.y); qf[11] = bfhi(qb.y);
    qf[12] = bflo(qb.z); qf[13] = bfhi(qb.z); qf[14] = bflo(qb.w); qf[15] = bfhi(qb.w);

    float acc[16];
    #pragma unroll
    for (int j = 0; j < 16; ++j) acc[j] = 0.0f;

    const int start = rowptr[wave], end = rowptr[wave + 1];

    #pragma unroll 2
    for (int i = start + sub; i < end; i += 8) {
        const int c = colsorted[i];
        const unsigned char* rec = kv + (size_t)c * KVREC;
        const uint4 kb = *reinterpret_cast<const uint4*>(rec + s * 16);
        const uint4 v0 = *reinterpret_cast<const uint4*>(rec + 128 + s * 32);
        const uint4 v1 = *reinterpret_cast<const uint4*>(rec + 128 + s * 32 + 16);

        float kf[16];
        fp8x4d(kb.x, kf);      fp8x4d(kb.y, kf + 4);
        fp8x4d(kb.z, kf + 8);  fp8x4d(kb.w, kf + 12);

        float dot = 0.0f;
        #pragma unroll
        for (int j = 0; j < 16; ++j) dot = fmaf(qf[j], kf[j], dot);
        dot += __shfl_xor(dot, 1);
        dot += __shfl_xor(dot, 2);
        dot += __shfl_xor(dot, 4);
        const float coef = 1.0f / (1.0f + __expf(-dot * 0.08838834764831845f));

        acc[0]  = fmaf(coef, bflo(v0.x), acc[0]);
        acc[1]  = fmaf(coef, bfhi(v0.x), acc[1]);
        acc[2]  = fmaf(coef, bflo(v0.y), acc[2]);
        acc[3]  = fmaf(coef, bfhi(v0.y), acc[3]);
        acc[4]  = fmaf(coef, bflo(v0.z), acc[4]);
        acc[5]  = fmaf(coef, bfhi(v0.z), acc[5]);
        acc[6]  = fmaf(coef, bflo(v0.w), acc[6]);
        acc[7]  = fmaf(coef, bfhi(v0.w), acc[7]);
        acc[8]  = fmaf(coef, bflo(v1.x), acc[8]);
        acc[9]  = fmaf(coef, bfhi(v1.x), acc[9]);
        acc[10] = fmaf(coef, bflo(v1.y), acc[10]);
        acc[11] = fmaf(coef, bfhi(v1.y), acc[11]);
        acc[12] = fmaf(coef, bflo(v1.z), acc[12]);
        acc[13] = fmaf(coef, bfhi(v1.z), acc[13]);
        acc[14] = fmaf(coef, bflo(v1.w), acc[14]);
        acc[15] = fmaf(coef, bfhi(v1.w), acc[15]);
    }

    #pragma unroll
    for (int j = 0; j < 16; ++j) {
        acc[j] += __shfl_xor(acc[j], 8);
        acc[j] += __shfl_xor(acc[j], 16);
        acc[j] += __shfl_xor(acc[j], 32);
    }

    if (sub == 0) {
        float* op = out + (size_t)wave * D + s * 16;
        float4 o0 = {acc[0],  acc[1],  acc[2],  acc[3]};
        float4 o1 = {acc[4],  acc[5],  acc[6],  acc[7]};
        float4 o2 = {acc[8],  acc[9],  acc[10], acc[11]};
        float4 o3 = {acc[12], acc[13], acc[14], acc[15]};
        *reinterpret_cast<float4*>(op)      = o0;
        *reinterpret_cast<float4*>(op + 4)  = o1;
        *reinterpret_cast<float4*>(op + 8)  = o2;
        *reinterpret_cast<float4*>(op + 12) = o3;
    }
}

extern "C" void kernel_launch(void* const* d_in, const int* in_sizes, int n_in,
                              void* d_out, int out_size, void* d_ws, size_t ws_size,
                              hipStream_t stream) {
    const float* query  = (const float*)d_in[0];
    const float* memory = (const float*)d_in[1];
    const float* Wq     = (const float*)d_in[2];
    const float* bq     = (const float*)d_in[3];
    const float* Wk     = (const float*)d_in[4];
    const float* bk     = (const float*)d_in[5];
    const float* Wv     = (const float*)d_in[6];
    const float* bv     = (const float*)d_in[7];
    const int*   erows  = (const int*)d_in[8];
    const int*   ecols  = (const int*)d_in[9];

    const int n  = in_sizes[0] / D;   // 100000
    const int m  = in_sizes[1] / D;   // 100000
    const int nE = in_sizes[8];       // 1600000

    char* base = (char*)d_ws;
    size_t off = 0;
    auto carve = [&](size_t bytes) -> char* {
        char* p = base + off;
        off = (off + bytes + 255) & ~(size_t)255;
        return p;
    };
    unsigned short* q   = (unsigned short*)carve((size_t)n * D * sizeof(unsigned short));
    unsigned char*  kv  = (unsigned char*) carve((size_t)m * KVREC);
    unsigned short* F   = (unsigned short*)carve(3 * 32 * 64 * 8 * sizeof(unsigned short));
    int*   rowptr    = (int*)carve((size_t)(n + 1) * sizeof(int));
    int*   cnt       = (int*)carve((size_t)(n + 1) * sizeof(int));
    int*   rank      = (int*)carve((size_t)nE * sizeof(int));
    int*   bsum      = (int*)carve(256 * sizeof(int));
    int*   colsorted = (int*)carve((size_t)nE * sizeof(int));
    float* out       = (float*)d_out;

    unsigned short* Fq = F;
    unsigned short* Fk = F + 16384;
    unsigned short* Fv = F + 32768;

    dim3 blk(256);
    const int nbScan = (n + 1023) / 1024;            // 98 <= 256
    const int nbE8   = ((nE + 1023) / 1024) * 8;     // hist blocks (4 edges/thr)
    const int nbSc   = ((nE + 2047) / 2048) * 8;     // scatter blocks (8 edges/thr)
    const int nbQ    = (n + 127) / 128;
    const int nbM    = (m + 127) / 128;

    // 1) zero counters
    hipMemsetAsync(cnt, 0, (size_t)(n + 1) * sizeof(int), stream);
    // 2) hist(+rank) || prepack
    fused_pre_kernel<<<dim3(nbE8 + 192), blk, 0, stream>>>(
        erows, cnt, rank, nE, n, nbE8, Wq, Wk, Wv, F);
    // 3) block sums
    scan_bsum_kernel<<<dim3(nbScan), blk, 0, stream>>>(cnt, bsum, n);
    // 4) rowptr (inline boff re-scan)
    scan_write2_kernel<<<dim3(nbScan), blk, 0, stream>>>(cnt, bsum, nbScan, rowptr, n);
    // 5) scatter (atomic-free, rank-based)
    scatter_kernel<<<dim3(nbSc), blk, 0, stream>>>(erows, ecols, rank, rowptr, colsorted, nE, n);
    // 6) projections q || kv (LDS-staged A-tiles)
    proj_kernel<<<dim3(nbQ + nbM), blk, 0, stream>>>(
        query, memory, Fq, bq, q, Fk, bk, Fv, bv, kv, n, m, nbQ);
    // 7) aggregation (writes all outputs; no out memset needed)
    agg_kernel<<<dim3((n * 64 + 255) / 256), blk, 0, stream>>>(q, kv, rowptr, colsorted, out, n);
}

// Round 13
// 285.997 us; speedup vs baseline: 1.1401x; 1.0156x over previous
//
#include <hip/hip_runtime.h>
#include <hip/hip_bf16.h>
#include <math.h>

#ifndef __has_builtin
#define __has_builtin(x) 0
#endif
#if __has_builtin(__builtin_amdgcn_cvt_pk_fp8_f32) && __has_builtin(__builtin_amdgcn_cvt_pk_f32_fp8)
#define FP8_HW 1
#else
#include <hip/hip_fp8.h>
#endif

#define D 128
#define KVREC 384   // 128 B k (fp8 e4m3) + 256 B v (bf16)

typedef float f32x16 __attribute__((ext_vector_type(16)));
typedef float f32x2  __attribute__((ext_vector_type(2)));
typedef short bf16x8 __attribute__((ext_vector_type(8)));

// gelu tanh-approx, exact rewrite: 0.5x(1+tanh(u)) == x / (1 + e^{-2u})
__device__ __forceinline__ float gelu_fast(float x) {
    float u = 0.7978845608028654f * (x + 0.044715f * x * x * x);
    return x / (1.0f + __expf(-2.0f * u));
}

__device__ __forceinline__ unsigned short f2bf(float f) {
    union { float f; unsigned u; } x; x.f = f;
    unsigned r = x.u + 0x7fff + ((x.u >> 16) & 1);   // RNE
    return (unsigned short)(r >> 16);
}

__device__ __forceinline__ float bflo(unsigned u) { return __uint_as_float(u << 16); }
__device__ __forceinline__ float bfhi(unsigned u) { return __uint_as_float(u & 0xffff0000u); }

__device__ __forceinline__ unsigned char f2fp8(float x) {
#ifdef FP8_HW
    return (unsigned char)(__builtin_amdgcn_cvt_pk_fp8_f32(x, x, 0, false) & 0xFF);
#else
    __hip_fp8_e4m3 h(x); return (unsigned char)h.__x;
#endif
}

__device__ __forceinline__ void fp8x4d(unsigned u, float* f) {
#ifdef FP8_HW
    f32x2 lo = __builtin_amdgcn_cvt_pk_f32_fp8((int)u, false);
    f32x2 hi = __builtin_amdgcn_cvt_pk_f32_fp8((int)u, true);
    f[0] = lo[0]; f[1] = lo[1]; f[2] = hi[0]; f[3] = hi[1];
#else
    #pragma unroll
    for (int i = 0; i < 4; ++i) {
        __hip_fp8_e4m3 h; h.__x = (unsigned char)((u >> (8 * i)) & 0xFF);
        f[i] = (float)h;
    }
#endif
}

// ================= fused_pre: hist+rank (blocks < nbE8) || prepack ==========

__global__ __launch_bounds__(256) void fused_pre_kernel(
    const int* __restrict__ rows, int* __restrict__ cnt, int* __restrict__ rank,
    int nE, int n, int nbE8,
    const float* __restrict__ W0, const float* __restrict__ W1,
    const float* __restrict__ W2, unsigned short* __restrict__ F)
{
    const int bid = blockIdx.x;
    if (bid < nbE8) {
        const int g  = bid & 7;
        const int lo = (int)(((long long)g * n) >> 3);
        const int hi = (int)(((long long)(g + 1) * n) >> 3);
        const int idx = (bid >> 3) * 1024 + threadIdx.x * 4;
        if (idx + 3 < nE) {
            int4 r4 = *reinterpret_cast<const int4*>(rows + idx);
            int rk[4] = {-1, -1, -1, -1};
            if (r4.x >= lo && r4.x < hi) rk[0] = atomicAdd(&cnt[r4.x], 1);
            if (r4.y >= lo && r4.y < hi) rk[1] = atomicAdd(&cnt[r4.y], 1);
            if (r4.z >= lo && r4.z < hi) rk[2] = atomicAdd(&cnt[r4.z], 1);
            if (r4.w >= lo && r4.w < hi) rk[3] = atomicAdd(&cnt[r4.w], 1);
            #pragma unroll
            for (int j = 0; j < 4; ++j)
                if (rk[j] >= 0) rank[idx + j] = rk[j];
        } else {
            for (int i = 0; i < 4; ++i)
                if (idx + i < nE) {
                    int r = rows[idx + i];
                    if (r >= lo && r < hi) rank[idx + i] = atomicAdd(&cnt[r], 1);
                }
        }
    } else {
        int gidx = (bid - nbE8) * 256 + threadIdx.x;
        if (gidx >= 3 * 32 * 64 * 8) return;
        const int midx = gidx >> 14;
        const int idx  = gidx & 16383;
        const float* W = midx == 0 ? W0 : (midx == 1 ? W1 : W2);
        int j  = idx & 7;
        int l  = (idx >> 3) & 63;
        int kt = (idx >> 9) & 7;
        int ct = idx >> 12;
        int kk = kt * 16 + (l >> 5) * 8 + j;
        int c  = ct * 32 + (l & 31);
        F[gidx] = f2bf(W[kk * D + c]);
    }
}

// ================= scan: block sums, then write (with inline boff re-scan) ===

__global__ __launch_bounds__(256) void scan_bsum_kernel(
    const int* __restrict__ cnt, int* __restrict__ bsum, int n)
{
    __shared__ int s[256];
    const int t = threadIdx.x;
    const int base = blockIdx.x * 1024 + t * 4;
    int sum = 0;
    if (base + 3 < n) {
        int4 c4 = *reinterpret_cast<const int4*>(cnt + base);
        sum = c4.x + c4.y + c4.z + c4.w;
    } else {
        for (int i = 0; i < 4; ++i) if (base + i < n) sum += cnt[base + i];
    }
    s[t] = sum;
    __syncthreads();
    #pragma unroll
    for (int off = 128; off > 0; off >>= 1) {
        if (t < off) s[t] += s[t + off];
        __syncthreads();
    }
    if (t == 0) bsum[blockIdx.x] = s[0];
}

__global__ __launch_bounds__(256) void scan_write2_kernel(
    const int* __restrict__ cnt, const int* __restrict__ bsum, int nb,
    int* __restrict__ rowptr, int n)
{
    __shared__ int s[256];
    const int t = threadIdx.x;

    s[t] = (t < nb) ? bsum[t] : 0;
    __syncthreads();
    #pragma unroll
    for (int off = 1; off < 256; off <<= 1) {
        int v = (t >= off) ? s[t - off] : 0;
        __syncthreads();
        s[t] += v;
        __syncthreads();
    }
    const int boffv = (blockIdx.x > 0) ? s[blockIdx.x - 1] : 0;  // exclusive
    const int total = s[255];
    if (blockIdx.x == 0 && t == 0) rowptr[n] = total;
    __syncthreads();

    const int base = blockIdx.x * 1024 + t * 4;
    int c[4] = {0, 0, 0, 0};
    if (base + 3 < n) {
        int4 c4 = *reinterpret_cast<const int4*>(cnt + base);
        c[0] = c4.x; c[1] = c4.y; c[2] = c4.z; c[3] = c4.w;
    } else {
        for (int i = 0; i < 4; ++i) if (base + i < n) c[i] = cnt[base + i];
    }
    const int tsum = c[0] + c[1] + c[2] + c[3];
    s[t] = tsum;
    __syncthreads();
    #pragma unroll
    for (int off = 1; off < 256; off <<= 1) {
        int v = (t >= off) ? s[t - off] : 0;
        __syncthreads();
        s[t] += v;
        __syncthreads();
    }
    int run = boffv + s[t] - tsum;
    int w0 = run;
    int w1 = run + c[0];
    int w2 = w1 + c[1];
    int w3 = w2 + c[2];
    if (base + 3 < n) {
        *reinterpret_cast<int4*>(rowptr + base) = make_int4(w0, w1, w2, w3);
    } else {
        int w[4] = {w0, w1, w2, w3};
        for (int i = 0; i < 4; ++i) if (base + i < n) rowptr[base + i] = w[i];
    }
}

// ================= scatter: rank-based, ATOMIC-FREE streaming ================

__global__ __launch_bounds__(256, 8) void scatter_kernel(
    const int* __restrict__ rows, const int* __restrict__ cols,
    const int* __restrict__ rank, const int* __restrict__ rowptr,
    int* __restrict__ colsorted, int nE, int n)
{
    const int g  = blockIdx.x & 7;
    const int lo = (int)(((long long)g * n) >> 3);
    const int hi = (int)(((long long)(g + 1) * n) >> 3);
    const int idx = (blockIdx.x >> 3) * 2048 + threadIdx.x * 8;
    if (idx + 7 < nE) {
        int4 ra = *reinterpret_cast<const int4*>(rows + idx);
        int4 rb = *reinterpret_cast<const int4*>(rows + idx + 4);
        int4 ca = *reinterpret_cast<const int4*>(cols + idx);
        int4 cb = *reinterpret_cast<const int4*>(cols + idx + 4);
        int4 ka = *reinterpret_cast<const int4*>(rank + idx);
        int4 kb = *reinterpret_cast<const int4*>(rank + idx + 4);
        int r[8] = {ra.x, ra.y, ra.z, ra.w, rb.x, rb.y, rb.z, rb.w};
        int c[8] = {ca.x, ca.y, ca.z, ca.w, cb.x, cb.y, cb.z, cb.w};
        int k[8] = {ka.x, ka.y, ka.z, ka.w, kb.x, kb.y, kb.z, kb.w};
        int p[8];
        #pragma unroll
        for (int j = 0; j < 8; ++j)
            p[j] = (r[j] >= lo && r[j] < hi) ? rowptr[r[j]] + k[j] : -1;
        #pragma unroll
        for (int j = 0; j < 8; ++j)
            if (p[j] >= 0) colsorted[p[j]] = c[j];
    } else {
        for (int i = 0; i < 8; ++i)
            if (idx + i < nE) {
                int r = rows[idx + i];
                if (r >= lo && r < hi)
                    colsorted[rowptr[r] + rank[idx + i]] = cols[idx + i];
            }
    }
}

// ================= proj: 64-row tiles, ct-split waves, low VGPR ==============
// R13: remove BOTH occupancy caps. 64-row LDS tile (17.4 KB -> 8 blocks/CU)
// and one live f32x16 acc per wave (no ct unroll; wave w owns rows
// (w>>1)*32..+31 and cts (w&1)*2..+1) -> VGPR ~48-64 -> 8 waves/SIMD.
// R12's proj: VGPR=112 (4 unrolled ct accs) + 34.8 KB = 16 waves/CU cap.

__global__ __launch_bounds__(256) void proj_kernel(
    const float* __restrict__ Xq, const float* __restrict__ Xm,
    const unsigned short* __restrict__ Fq, const float* __restrict__ bq,
    unsigned short* __restrict__ qout,
    const unsigned short* __restrict__ Fk, const float* __restrict__ bk,
    const unsigned short* __restrict__ Fv, const float* __restrict__ bv,
    unsigned char* __restrict__ kv,
    int n, int m, int nbQ)
{
    __shared__ __align__(16) unsigned short sX[64][136];   // 17.4 KB
    const int bid = blockIdx.x;
    const int tid = threadIdx.x;

    const bool isQ = bid < nbQ;
    const int row0 = (isQ ? bid : bid - nbQ) * 64;
    const int nn   = isQ ? n : m;
    const float* X = isQ ? Xq : Xm;

    // stage 64x128 f32 -> bf16 LDS, coalesced float4 reads
    #pragma unroll
    for (int p = 0; p < 8; ++p) {
        int flat = p * 256 + tid;
        int r = flat >> 5;
        int c = (flat & 31) * 4;
        int gr = row0 + r; if (gr >= nn) gr = nn - 1;   // clamp; stores guarded
        float4 x4 = *reinterpret_cast<const float4*>(X + (size_t)gr * D + c);
        uint2 pk;
        pk.x = (unsigned)f2bf(x4.x) | ((unsigned)f2bf(x4.y) << 16);
        pk.y = (unsigned)f2bf(x4.z) | ((unsigned)f2bf(x4.w) << 16);
        *reinterpret_cast<uint2*>(&sX[r][c]) = pk;
    }
    __syncthreads();

    const int l   = tid & 63;
    const int w   = tid >> 6;
    const int rg  = w >> 1;            // row group 0..1 (32 rows each)
    const int ct0 = (w & 1) * 2;       // this wave's first col-tile
    const int arow = rg * 32 + (l & 31);
    const int rowbase = row0 + rg * 32;

    bf16x8 af[8];
    #pragma unroll
    for (int kt = 0; kt < 8; ++kt)
        af[kt] = *reinterpret_cast<const bf16x8*>(&sX[arow][kt * 16 + (l >> 5) * 8]);

    if (isQ) {
        #pragma unroll 1
        for (int ci = 0; ci < 2; ++ci) {
            const int ct = ct0 + ci;
            f32x16 acc = {};
            #pragma unroll
            for (int kt = 0; kt < 8; ++kt) {
                bf16x8 bfr = *reinterpret_cast<const bf16x8*>(Fq + ((size_t)((ct * 8 + kt) * 64 + l) * 8));
                acc = __builtin_amdgcn_mfma_f32_32x32x16_bf16(af[kt], bfr, acc, 0, 0, 0);
            }
            const int col = ct * 32 + (l & 31);
            const float bb = bq[col];
            #pragma unroll
            for (int reg = 0; reg < 16; ++reg) {
                int r  = (reg & 3) + 8 * (reg >> 2) + 4 * (l >> 5);
                int gr = rowbase + r;
                if (gr < nn)
                    qout[(size_t)gr * D + col] = f2bf(gelu_fast(acc[reg] + bb));
            }
        }
    } else {
        #pragma unroll 1
        for (int mat = 0; mat < 2; ++mat) {
            const unsigned short* F = mat ? Fv : Fk;
            const float* bias       = mat ? bv : bk;
            #pragma unroll 1
            for (int ci = 0; ci < 2; ++ci) {
                const int ct = ct0 + ci;
                f32x16 acc = {};
                #pragma unroll
                for (int kt = 0; kt < 8; ++kt) {
                    bf16x8 bfr = *reinterpret_cast<const bf16x8*>(F + ((size_t)((ct * 8 + kt) * 64 + l) * 8));
                    acc = __builtin_amdgcn_mfma_f32_32x32x16_bf16(af[kt], bfr, acc, 0, 0, 0);
                }
                const int col = ct * 32 + (l & 31);
                const float bb = bias[col];
                #pragma unroll
                for (int reg = 0; reg < 16; ++reg) {
                    int r  = (reg & 3) + 8 * (reg >> 2) + 4 * (l >> 5);
                    int gr = rowbase + r;
                    if (gr < nn) {
                        unsigned char* rec = kv + (size_t)gr * KVREC;
                        float val = gelu_fast(acc[reg] + bb);
                        if (mat == 0)
                            rec[col] = f2fp8(val);
                        else
                            reinterpret_cast<unsigned short*>(rec + 128)[col] = f2bf(val);
                    }
                }
            }
        }
    }
}

// ===== aggregation (R11 version): one wave/row, 4 edge slots x 16 dim lanes ==
// q bf16 [n][128]; kv record [m][384]: k fp8 (128 B) then v bf16 (256 B)
__global__ __launch_bounds__(256) void agg_kernel(
    const unsigned short* __restrict__ q, const unsigned char* __restrict__ kv,
    const int* __restrict__ rowptr, const int* __restrict__ colsorted,
    float* __restrict__ out, int n)
{
    const int wave = (blockIdx.x * 256 + threadIdx.x) >> 6;
    if (wave >= n) return;
    const int lane = threadIdx.x & 63;
    const int sub  = lane >> 4;
    const int l    = lane & 15;

    const uint4 qa = *reinterpret_cast<const uint4*>(q + (size_t)wave * D + l * 8);
    float qf[8];
    qf[0] = bflo(qa.x); qf[1] = bfhi(qa.x);
    qf[2] = bflo(qa.y); qf[3] = bfhi(qa.y);
    qf[4] = bflo(qa.z); qf[5] = bfhi(qa.z);
    qf[6] = bflo(qa.w); qf[7] = bfhi(qa.w);

    float acc[8] = {0.f,0.f,0.f,0.f,0.f,0.f,0.f,0.f};
    const int start = rowptr[wave], end = rowptr[wave + 1];

    #pragma unroll 2
    for (int i = start + sub; i < end; i += 4) {
        const int c = colsorted[i];
        const unsigned char* rec = kv + (size_t)c * KVREC;
        const uint2 kb = *reinterpret_cast<const uint2*>(rec + l * 8);
        const uint4 vb = *reinterpret_cast<const uint4*>(rec + 128 + l * 16);

        float kf[8];
        fp8x4d(kb.x, kf); fp8x4d(kb.y, kf + 4);

        float dot = 0.0f;
        #pragma unroll
        for (int j = 0; j < 8; ++j) dot = fmaf(qf[j], kf[j], dot);
        dot += __shfl_xor(dot, 1);
        dot += __shfl_xor(dot, 2);
        dot += __shfl_xor(dot, 4);
        dot += __shfl_xor(dot, 8);
        const float coef = 1.0f / (1.0f + __expf(-dot * 0.08838834764831845f));

        acc[0] = fmaf(coef, bflo(vb.x), acc[0]);
        acc[1] = fmaf(coef, bfhi(vb.x), acc[1]);
        acc[2] = fmaf(coef, bflo(vb.y), acc[2]);
        acc[3] = fmaf(coef, bfhi(vb.y), acc[3]);
        acc[4] = fmaf(coef, bflo(vb.z), acc[4]);
        acc[5] = fmaf(coef, bfhi(vb.z), acc[5]);
        acc[6] = fmaf(coef, bflo(vb.w), acc[6]);
        acc[7] = fmaf(coef, bfhi(vb.w), acc[7]);
    }

    #pragma unroll
    for (int j = 0; j < 8; ++j) {
        acc[j] += __shfl_xor(acc[j], 16);
        acc[j] += __shfl_xor(acc[j], 32);
    }

    if (sub == 0) {
        float* op = out + (size_t)wave * D + l * 8;
        float4 o0 = {acc[0], acc[1], acc[2], acc[3]};
        float4 o1 = {acc[4], acc[5], acc[6], acc[7]};
        *reinterpret_cast<float4*>(op)     = o0;
        *reinterpret_cast<float4*>(op + 4) = o1;
    }
}

extern "C" void kernel_launch(void* const* d_in, const int* in_sizes, int n_in,
                              void* d_out, int out_size, void* d_ws, size_t ws_size,
                              hipStream_t stream) {
    const float* query  = (const float*)d_in[0];
    const float* memory = (const float*)d_in[1];
    const float* Wq     = (const float*)d_in[2];
    const float* bq     = (const float*)d_in[3];
    const float* Wk     = (const float*)d_in[4];
    const float* bk     = (const float*)d_in[5];
    const float* Wv     = (const float*)d_in[6];
    const float* bv     = (const float*)d_in[7];
    const int*   erows  = (const int*)d_in[8];
    const int*   ecols  = (const int*)d_in[9];

    const int n  = in_sizes[0] / D;   // 100000
    const int m  = in_sizes[1] / D;   // 100000
    const int nE = in_sizes[8];       // 1600000

    char* base = (char*)d_ws;
    size_t off = 0;
    auto carve = [&](size_t bytes) -> char* {
        char* p = base + off;
        off = (off + bytes + 255) & ~(size_t)255;
        return p;
    };
    unsigned short* q   = (unsigned short*)carve((size_t)n * D * sizeof(unsigned short));
    unsigned char*  kv  = (unsigned char*) carve((size_t)m * KVREC);
    unsigned short* F   = (unsigned short*)carve(3 * 32 * 64 * 8 * sizeof(unsigned short));
    int*   rowptr    = (int*)carve((size_t)(n + 1) * sizeof(int));
    int*   cnt       = (int*)carve((size_t)(n + 1) * sizeof(int));
    int*   rank      = (int*)carve((size_t)nE * sizeof(int));
    int*   bsum      = (int*)carve(256 * sizeof(int));
    int*   colsorted = (int*)carve((size_t)nE * sizeof(int));
    float* out       = (float*)d_out;

    unsigned short* Fq = F;
    unsigned short* Fk = F + 16384;
    unsigned short* Fv = F + 32768;

    dim3 blk(256);
    const int nbScan = (n + 1023) / 1024;            // 98 <= 256
    const int nbE8   = ((nE + 1023) / 1024) * 8;     // hist blocks (4 edges/thr)
    const int nbSc   = ((nE + 2047) / 2048) * 8;     // scatter blocks (8 edges/thr)
    const int nbQ    = (n + 63) / 64;                // 64-row proj tiles
    const int nbM    = (m + 63) / 64;

    // 1) zero counters
    hipMemsetAsync(cnt, 0, (size_t)(n + 1) * sizeof(int), stream);
    // 2) hist(+rank) || prepack
    fused_pre_kernel<<<dim3(nbE8 + 192), blk, 0, stream>>>(
        erows, cnt, rank, nE, n, nbE8, Wq, Wk, Wv, F);
    // 3) block sums
    scan_bsum_kernel<<<dim3(nbScan), blk, 0, stream>>>(cnt, bsum, n);
    // 4) rowptr (inline boff re-scan)
    scan_write2_kernel<<<dim3(nbScan), blk, 0, stream>>>(cnt, bsum, nbScan, rowptr, n);
    // 5) scatter (atomic-free, rank-based)
    scatter_kernel<<<dim3(nbSc), blk, 0, stream>>>(erows, ecols, rank, rowptr, colsorted, nE, n);
    // 6) projections q || kv (64-row tiles, ct-split waves)
    proj_kernel<<<dim3(nbQ + nbM), blk, 0, stream>>>(
        query, memory, Fq, bq, q, Fk, bk, Fv, bv, kv, n, m, nbQ);
    // 7) aggregation (writes all outputs; no out memset needed)
    agg_kernel<<<dim3((n * 64 + 255) / 256), blk, 0, stream>>>(q, kv, rowptr, colsorted, out, n);
}

// Round 14
// 271.814 us; speedup vs baseline: 1.1996x; 1.0522x over previous
//
#include <hip/hip_runtime.h>
#include <hip/hip_bf16.h>
#include <math.h>

#ifndef __has_builtin
#define __has_builtin(x) 0
#endif
#if __has_builtin(__builtin_amdgcn_cvt_pk_fp8_f32) && __has_builtin(__builtin_amdgcn_cvt_pk_f32_fp8)
#define FP8_HW 1
#else
#include <hip/hip_fp8.h>
#endif

#define D 128
#define KVREC 384   // 128 B k (fp8 e4m3) + 256 B v (bf16)

typedef float f32x16 __attribute__((ext_vector_type(16)));
typedef float f32x2  __attribute__((ext_vector_type(2)));
typedef short bf16x8 __attribute__((ext_vector_type(8)));

// gelu tanh-approx, exact rewrite: 0.5x(1+tanh(u)) == x / (1 + e^{-2u})
__device__ __forceinline__ float gelu_fast(float x) {
    float u = 0.7978845608028654f * (x + 0.044715f * x * x * x);
    return x / (1.0f + __expf(-2.0f * u));
}

__device__ __forceinline__ unsigned short f2bf(float f) {
    union { float f; unsigned u; } x; x.f = f;
    unsigned r = x.u + 0x7fff + ((x.u >> 16) & 1);   // RNE
    return (unsigned short)(r >> 16);
}

__device__ __forceinline__ float bflo(unsigned u) { return __uint_as_float(u << 16); }
__device__ __forceinline__ float bfhi(unsigned u) { return __uint_as_float(u & 0xffff0000u); }

__device__ __forceinline__ unsigned char f2fp8(float x) {
#ifdef FP8_HW
    return (unsigned char)(__builtin_amdgcn_cvt_pk_fp8_f32(x, x, 0, false) & 0xFF);
#else
    __hip_fp8_e4m3 h(x); return (unsigned char)h.__x;
#endif
}

__device__ __forceinline__ void fp8x4d(unsigned u, float* f) {
#ifdef FP8_HW
    f32x2 lo = __builtin_amdgcn_cvt_pk_f32_fp8((int)u, false);
    f32x2 hi = __builtin_amdgcn_cvt_pk_f32_fp8((int)u, true);
    f[0] = lo[0]; f[1] = lo[1]; f[2] = hi[0]; f[3] = hi[1];
#else
    #pragma unroll
    for (int i = 0; i < 4; ++i) {
        __hip_fp8_e4m3 h; h.__x = (unsigned char)((u >> (8 * i)) & 0xFF);
        f[i] = (float)h;
    }
#endif
}

// ================= fused_pre: hist+rank (blocks < nbE8) || prepack ==========

__global__ __launch_bounds__(256) void fused_pre_kernel(
    const int* __restrict__ rows, int* __restrict__ cnt, int* __restrict__ rank,
    int nE, int n, int nbE8,
    const float* __restrict__ W0, const float* __restrict__ W1,
    const float* __restrict__ W2, unsigned short* __restrict__ F)
{
    const int bid = blockIdx.x;
    if (bid < nbE8) {
        const int g  = bid & 7;
        const int lo = (int)(((long long)g * n) >> 3);
        const int hi = (int)(((long long)(g + 1) * n) >> 3);
        const int idx = (bid >> 3) * 1024 + threadIdx.x * 4;
        if (idx + 3 < nE) {
            int4 r4 = *reinterpret_cast<const int4*>(rows + idx);
            int rk[4] = {-1, -1, -1, -1};
            if (r4.x >= lo && r4.x < hi) rk[0] = atomicAdd(&cnt[r4.x], 1);
            if (r4.y >= lo && r4.y < hi) rk[1] = atomicAdd(&cnt[r4.y], 1);
            if (r4.z >= lo && r4.z < hi) rk[2] = atomicAdd(&cnt[r4.z], 1);
            if (r4.w >= lo && r4.w < hi) rk[3] = atomicAdd(&cnt[r4.w], 1);
            #pragma unroll
            for (int j = 0; j < 4; ++j)
                if (rk[j] >= 0) rank[idx + j] = rk[j];
        } else {
            for (int i = 0; i < 4; ++i)
                if (idx + i < nE) {
                    int r = rows[idx + i];
                    if (r >= lo && r < hi) rank[idx + i] = atomicAdd(&cnt[r], 1);
                }
        }
    } else {
        int gidx = (bid - nbE8) * 256 + threadIdx.x;
        if (gidx >= 3 * 32 * 64 * 8) return;
        const int midx = gidx >> 14;
        const int idx  = gidx & 16383;
        const float* W = midx == 0 ? W0 : (midx == 1 ? W1 : W2);
        int j  = idx & 7;
        int l  = (idx >> 3) & 63;
        int kt = (idx >> 9) & 7;
        int ct = idx >> 12;
        int kk = kt * 16 + (l >> 5) * 8 + j;
        int c  = ct * 32 + (l & 31);
        F[gidx] = f2bf(W[kk * D + c]);
    }
}

// ================= scan: block sums, then write (with inline boff re-scan) ===

__global__ __launch_bounds__(256) void scan_bsum_kernel(
    const int* __restrict__ cnt, int* __restrict__ bsum, int n)
{
    __shared__ int s[256];
    const int t = threadIdx.x;
    const int base = blockIdx.x * 1024 + t * 4;
    int sum = 0;
    if (base + 3 < n) {
        int4 c4 = *reinterpret_cast<const int4*>(cnt + base);
        sum = c4.x + c4.y + c4.z + c4.w;
    } else {
        for (int i = 0; i < 4; ++i) if (base + i < n) sum += cnt[base + i];
    }
    s[t] = sum;
    __syncthreads();
    #pragma unroll
    for (int off = 128; off > 0; off >>= 1) {
        if (t < off) s[t] += s[t + off];
        __syncthreads();
    }
    if (t == 0) bsum[blockIdx.x] = s[0];
}

__global__ __launch_bounds__(256) void scan_write2_kernel(
    const int* __restrict__ cnt, const int* __restrict__ bsum, int nb,
    int* __restrict__ rowptr, int n)
{
    __shared__ int s[256];
    const int t = threadIdx.x;

    s[t] = (t < nb) ? bsum[t] : 0;
    __syncthreads();
    #pragma unroll
    for (int off = 1; off < 256; off <<= 1) {
        int v = (t >= off) ? s[t - off] : 0;
        __syncthreads();
        s[t] += v;
        __syncthreads();
    }
    const int boffv = (blockIdx.x > 0) ? s[blockIdx.x - 1] : 0;  // exclusive
    const int total = s[255];
    if (blockIdx.x == 0 && t == 0) rowptr[n] = total;
    __syncthreads();

    const int base = blockIdx.x * 1024 + t * 4;
    int c[4] = {0, 0, 0, 0};
    if (base + 3 < n) {
        int4 c4 = *reinterpret_cast<const int4*>(cnt + base);
        c[0] = c4.x; c[1] = c4.y; c[2] = c4.z; c[3] = c4.w;
    } else {
        for (int i = 0; i < 4; ++i) if (base + i < n) c[i] = cnt[base + i];
    }
    const int tsum = c[0] + c[1] + c[2] + c[3];
    s[t] = tsum;
    __syncthreads();
    #pragma unroll
    for (int off = 1; off < 256; off <<= 1) {
        int v = (t >= off) ? s[t - off] : 0;
        __syncthreads();
        s[t] += v;
        __syncthreads();
    }
    int run = boffv + s[t] - tsum;
    int w0 = run;
    int w1 = run + c[0];
    int w2 = w1 + c[1];
    int w3 = w2 + c[2];
    if (base + 3 < n) {
        *reinterpret_cast<int4*>(rowptr + base) = make_int4(w0, w1, w2, w3);
    } else {
        int w[4] = {w0, w1, w2, w3};
        for (int i = 0; i < 4; ++i) if (base + i < n) rowptr[base + i] = w[i];
    }
}

// ========== scatter: rank-based atomic-free, 4 slices (halved re-read) =======
// R14: atomics are gone (rank), so slicing only serves colsorted write
// locality; 4 slices halve the rows/cols/rank re-read (153.6 -> 76.8 MB,
// L3-served) at ~x2 write amp on only 6.4 MB.

__global__ __launch_bounds__(256, 8) void scatter_kernel(
    const int* __restrict__ rows, const int* __restrict__ cols,
    const int* __restrict__ rank, const int* __restrict__ rowptr,
    int* __restrict__ colsorted, int nE, int n)
{
    const int g  = blockIdx.x & 3;
    const int lo = (int)(((long long)g * n) >> 2);
    const int hi = (int)(((long long)(g + 1) * n) >> 2);
    const int idx = (blockIdx.x >> 2) * 2048 + threadIdx.x * 8;
    if (idx + 7 < nE) {
        int4 ra = *reinterpret_cast<const int4*>(rows + idx);
        int4 rb = *reinterpret_cast<const int4*>(rows + idx + 4);
        int4 ca = *reinterpret_cast<const int4*>(cols + idx);
        int4 cb = *reinterpret_cast<const int4*>(cols + idx + 4);
        int4 ka = *reinterpret_cast<const int4*>(rank + idx);
        int4 kb = *reinterpret_cast<const int4*>(rank + idx + 4);
        int r[8] = {ra.x, ra.y, ra.z, ra.w, rb.x, rb.y, rb.z, rb.w};
        int c[8] = {ca.x, ca.y, ca.z, ca.w, cb.x, cb.y, cb.z, cb.w};
        int k[8] = {ka.x, ka.y, ka.z, ka.w, kb.x, kb.y, kb.z, kb.w};
        int p[8];
        #pragma unroll
        for (int j = 0; j < 8; ++j)
            p[j] = (r[j] >= lo && r[j] < hi) ? rowptr[r[j]] + k[j] : -1;
        #pragma unroll
        for (int j = 0; j < 8; ++j)
            if (p[j] >= 0) colsorted[p[j]] = c[j];
    } else {
        for (int i = 0; i < 8; ++i)
            if (idx + i < nE) {
                int r = rows[idx + i];
                if (r >= lo && r < hi)
                    colsorted[rowptr[r] + rank[idx + i]] = cols[idx + i];
            }
    }
}

// ===== proj: grid-stride, double-buffered 32-row tiles (pipeline staging) ====
// R14: the untried axis. Each block loops over tiles; tile t+1's global loads
// are issued BEFORE tile t's compute (MFMA+gelu+stores), so HBM latency hides
// under compute instead of serializing at the barrier. 4 waves split the 4
// col-tiles of the same 32 rows; one live f32x16 acc.

__global__ __launch_bounds__(256) void proj_q_kernel(
    const float* __restrict__ X, const unsigned short* __restrict__ F1,
    const float* __restrict__ b1, unsigned short* __restrict__ C1,
    int n, int nTiles)
{
    __shared__ __align__(16) unsigned short sX[2][32][136];
    const int tid = threadIdx.x;
    const int l = tid & 63;
    const int ct = tid >> 6;           // wave w owns col-tile w
    const int arow = l & 31;

    int tile = blockIdx.x;
    if (tile >= nTiles) return;

    float4 r4[4];
    auto LOAD = [&](int t) {
        const int row0 = t * 32;
        #pragma unroll
        for (int p = 0; p < 4; ++p) {
            int flat = p * 256 + tid;
            int rr = flat >> 5;
            int cc = (flat & 31) * 4;
            int gr = row0 + rr; if (gr >= n) gr = n - 1;
            r4[p] = *reinterpret_cast<const float4*>(X + (size_t)gr * D + cc);
        }
    };
    auto STORE_LDS = [&](int buf) {
        #pragma unroll
        for (int p = 0; p < 4; ++p) {
            int flat = p * 256 + tid;
            int rr = flat >> 5;
            int cc = (flat & 31) * 4;
            uint2 pk;
            pk.x = (unsigned)f2bf(r4[p].x) | ((unsigned)f2bf(r4[p].y) << 16);
            pk.y = (unsigned)f2bf(r4[p].z) | ((unsigned)f2bf(r4[p].w) << 16);
            *reinterpret_cast<uint2*>(&sX[buf][rr][cc]) = pk;
        }
    };

    LOAD(tile);
    STORE_LDS(0);
    int cur = 0;
    const float bb = b1[ct * 32 + (l & 31)];
    while (tile < nTiles) {
        const int next = tile + gridDim.x;
        __syncthreads();                       // sX[cur] ready; cross-buffer hazards fenced
        if (next < nTiles) LOAD(next);         // in flight during compute

        const int row0 = tile * 32;
        bf16x8 af[8];
        #pragma unroll
        for (int kt = 0; kt < 8; ++kt)
            af[kt] = *reinterpret_cast<const bf16x8*>(&sX[cur][arow][kt * 16 + (l >> 5) * 8]);
        f32x16 acc = {};
        #pragma unroll
        for (int kt = 0; kt < 8; ++kt) {
            bf16x8 bfr = *reinterpret_cast<const bf16x8*>(F1 + ((size_t)((ct * 8 + kt) * 64 + l) * 8));
            acc = __builtin_amdgcn_mfma_f32_32x32x16_bf16(af[kt], bfr, acc, 0, 0, 0);
        }
        const int col = ct * 32 + (l & 31);
        #pragma unroll
        for (int reg = 0; reg < 16; ++reg) {
            int rr = (reg & 3) + 8 * (reg >> 2) + 4 * (l >> 5);
            int gr = row0 + rr;
            if (gr < n)
                C1[(size_t)gr * D + col] = f2bf(gelu_fast(acc[reg] + bb));
        }

        if (next < nTiles) STORE_LDS(cur ^ 1); // waits on LOAD(next) only here
        cur ^= 1;
        tile = next;
    }
}

__global__ __launch_bounds__(256) void proj_kv_kernel(
    const float* __restrict__ X,
    const unsigned short* __restrict__ Fk, const float* __restrict__ bk,
    const unsigned short* __restrict__ Fv, const float* __restrict__ bv,
    unsigned char* __restrict__ kv, int m, int nTiles)
{
    __shared__ __align__(16) unsigned short sX[2][32][136];
    const int tid = threadIdx.x;
    const int l = tid & 63;
    const int ct = tid >> 6;
    const int arow = l & 31;

    int tile = blockIdx.x;
    if (tile >= nTiles) return;

    float4 r4[4];
    auto LOAD = [&](int t) {
        const int row0 = t * 32;
        #pragma unroll
        for (int p = 0; p < 4; ++p) {
            int flat = p * 256 + tid;
            int rr = flat >> 5;
            int cc = (flat & 31) * 4;
            int gr = row0 + rr; if (gr >= m) gr = m - 1;
            r4[p] = *reinterpret_cast<const float4*>(X + (size_t)gr * D + cc);
        }
    };
    auto STORE_LDS = [&](int buf) {
        #pragma unroll
        for (int p = 0; p < 4; ++p) {
            int flat = p * 256 + tid;
            int rr = flat >> 5;
            int cc = (flat & 31) * 4;
            uint2 pk;
            pk.x = (unsigned)f2bf(r4[p].x) | ((unsigned)f2bf(r4[p].y) << 16);
            pk.y = (unsigned)f2bf(r4[p].z) | ((unsigned)f2bf(r4[p].w) << 16);
            *reinterpret_cast<uint2*>(&sX[buf][rr][cc]) = pk;
        }
    };

    LOAD(tile);
    STORE_LDS(0);
    int cur = 0;
    const int col = ct * 32 + (l & 31);
    const float bbk = bk[col];
    const float bbv = bv[col];
    while (tile < nTiles) {
        const int next = tile + gridDim.x;
        __syncthreads();
        if (next < nTiles) LOAD(next);

        const int row0 = tile * 32;
        bf16x8 af[8];
        #pragma unroll
        for (int kt = 0; kt < 8; ++kt)
            af[kt] = *reinterpret_cast<const bf16x8*>(&sX[cur][arow][kt * 16 + (l >> 5) * 8]);

        #pragma unroll 1
        for (int mat = 0; mat < 2; ++mat) {
            const unsigned short* F = mat ? Fv : Fk;
            const float bb          = mat ? bbv : bbk;
            f32x16 acc = {};
            #pragma unroll
            for (int kt = 0; kt < 8; ++kt) {
                bf16x8 bfr = *reinterpret_cast<const bf16x8*>(F + ((size_t)((ct * 8 + kt) * 64 + l) * 8));
                acc = __builtin_amdgcn_mfma_f32_32x32x16_bf16(af[kt], bfr, acc, 0, 0, 0);
            }
            #pragma unroll
            for (int reg = 0; reg < 16; ++reg) {
                int rr = (reg & 3) + 8 * (reg >> 2) + 4 * (l >> 5);
                int gr = row0 + rr;
                if (gr < m) {
                    unsigned char* rec = kv + (size_t)gr * KVREC;
                    float val = gelu_fast(acc[reg] + bb);
                    if (mat == 0)
                        rec[col] = f2fp8(val);
                    else
                        reinterpret_cast<unsigned short*>(rec + 128)[col] = f2bf(val);
                }
            }
        }

        if (next < nTiles) STORE_LDS(cur ^ 1);
        cur ^= 1;
        tile = next;
    }
}

// ===== aggregation (R11 version): one wave/row, 4 edge slots x 16 dim lanes ==
__global__ __launch_bounds__(256) void agg_kernel(
    const unsigned short* __restrict__ q, const unsigned char* __restrict__ kv,
    const int* __restrict__ rowptr, const int* __restrict__ colsorted,
    float* __restrict__ out, int n)
{
    const int wave = (blockIdx.x * 256 + threadIdx.x) >> 6;
    if (wave >= n) return;
    const int lane = threadIdx.x & 63;
    const int sub  = lane >> 4;
    const int l    = lane & 15;

    const uint4 qa = *reinterpret_cast<const uint4*>(q + (size_t)wave * D + l * 8);
    float qf[8];
    qf[0] = bflo(qa.x); qf[1] = bfhi(qa.x);
    qf[2] = bflo(qa.y); qf[3] = bfhi(qa.y);
    qf[4] = bflo(qa.z); qf[5] = bfhi(qa.z);
    qf[6] = bflo(qa.w); qf[7] = bfhi(qa.w);

    float acc[8] = {0.f,0.f,0.f,0.f,0.f,0.f,0.f,0.f};
    const int start = rowptr[wave], end = rowptr[wave + 1];

    #pragma unroll 2
    for (int i = start + sub; i < end; i += 4) {
        const int c = colsorted[i];
        const unsigned char* rec = kv + (size_t)c * KVREC;
        const uint2 kb = *reinterpret_cast<const uint2*>(rec + l * 8);
        const uint4 vb = *reinterpret_cast<const uint4*>(rec + 128 + l * 16);

        float kf[8];
        fp8x4d(kb.x, kf); fp8x4d(kb.y, kf + 4);

        float dot = 0.0f;
        #pragma unroll
        for (int j = 0; j < 8; ++j) dot = fmaf(qf[j], kf[j], dot);
        dot += __shfl_xor(dot, 1);
        dot += __shfl_xor(dot, 2);
        dot += __shfl_xor(dot, 4);
        dot += __shfl_xor(dot, 8);
        const float coef = 1.0f / (1.0f + __expf(-dot * 0.08838834764831845f));

        acc[0] = fmaf(coef, bflo(vb.x), acc[0]);
        acc[1] = fmaf(coef, bfhi(vb.x), acc[1]);
        acc[2] = fmaf(coef, bflo(vb.y), acc[2]);
        acc[3] = fmaf(coef, bfhi(vb.y), acc[3]);
        acc[4] = fmaf(coef, bflo(vb.z), acc[4]);
        acc[5] = fmaf(coef, bfhi(vb.z), acc[5]);
        acc[6] = fmaf(coef, bflo(vb.w), acc[6]);
        acc[7] = fmaf(coef, bfhi(vb.w), acc[7]);
    }

    #pragma unroll
    for (int j = 0; j < 8; ++j) {
        acc[j] += __shfl_xor(acc[j], 16);
        acc[j] += __shfl_xor(acc[j], 32);
    }

    if (sub == 0) {
        float* op = out + (size_t)wave * D + l * 8;
        float4 o0 = {acc[0], acc[1], acc[2], acc[3]};
        float4 o1 = {acc[4], acc[5], acc[6], acc[7]};
        *reinterpret_cast<float4*>(op)     = o0;
        *reinterpret_cast<float4*>(op + 4) = o1;
    }
}

extern "C" void kernel_launch(void* const* d_in, const int* in_sizes, int n_in,
                              void* d_out, int out_size, void* d_ws, size_t ws_size,
                              hipStream_t stream) {
    const float* query  = (const float*)d_in[0];
    const float* memory = (const float*)d_in[1];
    const float* Wq     = (const float*)d_in[2];
    const float* bq     = (const float*)d_in[3];
    const float* Wk     = (const float*)d_in[4];
    const float* bk     = (const float*)d_in[5];
    const float* Wv     = (const float*)d_in[6];
    const float* bv     = (const float*)d_in[7];
    const int*   erows  = (const int*)d_in[8];
    const int*   ecols  = (const int*)d_in[9];

    const int n  = in_sizes[0] / D;   // 100000
    const int m  = in_sizes[1] / D;   // 100000
    const int nE = in_sizes[8];       // 1600000

    char* base = (char*)d_ws;
    size_t off = 0;
    auto carve = [&](size_t bytes) -> char* {
        char* p = base + off;
        off = (off + bytes + 255) & ~(size_t)255;
        return p;
    };
    unsigned short* q   = (unsigned short*)carve((size_t)n * D * sizeof(unsigned short));
    unsigned char*  kv  = (unsigned char*) carve((size_t)m * KVREC);
    unsigned short* F   = (unsigned short*)carve(3 * 32 * 64 * 8 * sizeof(unsigned short));
    int*   rowptr    = (int*)carve((size_t)(n + 1) * sizeof(int));
    int*   cnt       = (int*)carve((size_t)(n + 1) * sizeof(int));
    int*   rank      = (int*)carve((size_t)nE * sizeof(int));
    int*   bsum      = (int*)carve(256 * sizeof(int));
    int*   colsorted = (int*)carve((size_t)nE * sizeof(int));
    float* out       = (float*)d_out;

    unsigned short* Fq = F;
    unsigned short* Fk = F + 16384;
    unsigned short* Fv = F + 32768;

    dim3 blk(256);
    const int nbScan = (n + 1023) / 1024;            // 98 <= 256
    const int nbE8   = ((nE + 1023) / 1024) * 8;     // hist blocks (4 edges/thr, 8 slices)
    const int nbSc   = ((nE + 2047) / 2048) * 4;     // scatter blocks (8 edges/thr, 4 slices)
    const int nTq    = (n + 31) / 32;                // 32-row proj tiles
    const int nTm    = (m + 31) / 32;

    // 1) zero counters
    hipMemsetAsync(cnt, 0, (size_t)(n + 1) * sizeof(int), stream);
    // 2) hist(+rank) || prepack
    fused_pre_kernel<<<dim3(nbE8 + 192), blk, 0, stream>>>(
        erows, cnt, rank, nE, n, nbE8, Wq, Wk, Wv, F);
    // 3) block sums
    scan_bsum_kernel<<<dim3(nbScan), blk, 0, stream>>>(cnt, bsum, n);
    // 4) rowptr (inline boff re-scan)
    scan_write2_kernel<<<dim3(nbScan), blk, 0, stream>>>(cnt, bsum, nbScan, rowptr, n);
    // 5) scatter (atomic-free, 4 slices)
    scatter_kernel<<<dim3(nbSc), blk, 0, stream>>>(erows, ecols, rank, rowptr, colsorted, nE, n);
    // 6) projections (grid-stride, double-buffered pipeline)
    proj_q_kernel<<<dim3(1024), blk, 0, stream>>>(query, Fq, bq, q, n, nTq);
    proj_kv_kernel<<<dim3(1024), blk, 0, stream>>>(memory, Fk, bk, Fv, bv, kv, m, nTm);
    // 7) aggregation (writes all outputs; no out memset needed)
    agg_kernel<<<dim3((n * 64 + 255) / 256), blk, 0, stream>>>(q, kv, rowptr, colsorted, out, n);
}

// Round 15
// 259.469 us; speedup vs baseline: 1.2566x; 1.0476x over previous
//
#include <hip/hip_runtime.h>
#include <hip/hip_bf16.h>
#include <math.h>

#ifndef __has_builtin
#define __has_builtin(x) 0
#endif
#if __has_builtin(__builtin_amdgcn_cvt_pk_fp8_f32) && __has_builtin(__builtin_amdgcn_cvt_pk_f32_fp8)
#define FP8_HW 1
#else
#include <hip/hip_fp8.h>
#endif

#define D 128
#define KVREC 384   // 128 B k (fp8 e4m3) + 256 B v (bf16)

typedef float f32x16 __attribute__((ext_vector_type(16)));
typedef float f32x2  __attribute__((ext_vector_type(2)));
typedef short bf16x8 __attribute__((ext_vector_type(8)));

// gelu tanh-approx, exact rewrite: 0.5x(1+tanh(u)) == x / (1 + e^{-2u})
__device__ __forceinline__ float gelu_fast(float x) {
    float u = 0.7978845608028654f * (x + 0.044715f * x * x * x);
    return x / (1.0f + __expf(-2.0f * u));
}

__device__ __forceinline__ unsigned short f2bf(float f) {
    union { float f; unsigned u; } x; x.f = f;
    unsigned r = x.u + 0x7fff + ((x.u >> 16) & 1);   // RNE
    return (unsigned short)(r >> 16);
}

__device__ __forceinline__ float bflo(unsigned u) { return __uint_as_float(u << 16); }
__device__ __forceinline__ float bfhi(unsigned u) { return __uint_as_float(u & 0xffff0000u); }

__device__ __forceinline__ unsigned char f2fp8(float x) {
#ifdef FP8_HW
    return (unsigned char)(__builtin_amdgcn_cvt_pk_fp8_f32(x, x, 0, false) & 0xFF);
#else
    __hip_fp8_e4m3 h(x); return (unsigned char)h.__x;
#endif
}

__device__ __forceinline__ void fp8x4d(unsigned u, float* f) {
#ifdef FP8_HW
    f32x2 lo = __builtin_amdgcn_cvt_pk_f32_fp8((int)u, false);
    f32x2 hi = __builtin_amdgcn_cvt_pk_f32_fp8((int)u, true);
    f[0] = lo[0]; f[1] = lo[1]; f[2] = hi[0]; f[3] = hi[1];
#else
    #pragma unroll
    for (int i = 0; i < 4; ++i) {
        __hip_fp8_e4m3 h; h.__x = (unsigned char)((u >> (8 * i)) & 0xFF);
        f[i] = (float)h;
    }
#endif
}

// ================= fused_pre: hist+rank (blocks < nbE8) || prepack ==========

__global__ __launch_bounds__(256) void fused_pre_kernel(
    const int* __restrict__ rows, int* __restrict__ cnt, int* __restrict__ rank,
    int nE, int n, int nbE8,
    const float* __restrict__ W0, const float* __restrict__ W1,
    const float* __restrict__ W2, unsigned short* __restrict__ F)
{
    const int bid = blockIdx.x;
    if (bid < nbE8) {
        const int g  = bid & 7;
        const int lo = (int)(((long long)g * n) >> 3);
        const int hi = (int)(((long long)(g + 1) * n) >> 3);
        const int idx = (bid >> 3) * 1024 + threadIdx.x * 4;
        if (idx + 3 < nE) {
            int4 r4 = *reinterpret_cast<const int4*>(rows + idx);
            int rk[4] = {-1, -1, -1, -1};
            if (r4.x >= lo && r4.x < hi) rk[0] = atomicAdd(&cnt[r4.x], 1);
            if (r4.y >= lo && r4.y < hi) rk[1] = atomicAdd(&cnt[r4.y], 1);
            if (r4.z >= lo && r4.z < hi) rk[2] = atomicAdd(&cnt[r4.z], 1);
            if (r4.w >= lo && r4.w < hi) rk[3] = atomicAdd(&cnt[r4.w], 1);
            #pragma unroll
            for (int j = 0; j < 4; ++j)
                if (rk[j] >= 0) rank[idx + j] = rk[j];
        } else {
            for (int i = 0; i < 4; ++i)
                if (idx + i < nE) {
                    int r = rows[idx + i];
                    if (r >= lo && r < hi) rank[idx + i] = atomicAdd(&cnt[r], 1);
                }
        }
    } else {
        int gidx = (bid - nbE8) * 256 + threadIdx.x;
        if (gidx >= 3 * 32 * 64 * 8) return;
        const int midx = gidx >> 14;
        const int idx  = gidx & 16383;
        const float* W = midx == 0 ? W0 : (midx == 1 ? W1 : W2);
        int j  = idx & 7;
        int l  = (idx >> 3) & 63;
        int kt = (idx >> 9) & 7;
        int ct = idx >> 12;
        int kk = kt * 16 + (l >> 5) * 8 + j;
        int c  = ct * 32 + (l & 31);
        F[gidx] = f2bf(W[kk * D + c]);
    }
}

// ================= scan: block sums, then write (with inline boff re-scan) ===

__global__ __launch_bounds__(256) void scan_bsum_kernel(
    const int* __restrict__ cnt, int* __restrict__ bsum, int n)
{
    __shared__ int s[256];
    const int t = threadIdx.x;
    const int base = blockIdx.x * 1024 + t * 4;
    int sum = 0;
    if (base + 3 < n) {
        int4 c4 = *reinterpret_cast<const int4*>(cnt + base);
        sum = c4.x + c4.y + c4.z + c4.w;
    } else {
        for (int i = 0; i < 4; ++i) if (base + i < n) sum += cnt[base + i];
    }
    s[t] = sum;
    __syncthreads();
    #pragma unroll
    for (int off = 128; off > 0; off >>= 1) {
        if (t < off) s[t] += s[t + off];
        __syncthreads();
    }
    if (t == 0) bsum[blockIdx.x] = s[0];
}

__global__ __launch_bounds__(256) void scan_write2_kernel(
    const int* __restrict__ cnt, const int* __restrict__ bsum, int nb,
    int* __restrict__ rowptr, int n)
{
    __shared__ int s[256];
    const int t = threadIdx.x;

    s[t] = (t < nb) ? bsum[t] : 0;
    __syncthreads();
    #pragma unroll
    for (int off = 1; off < 256; off <<= 1) {
        int v = (t >= off) ? s[t - off] : 0;
        __syncthreads();
        s[t] += v;
        __syncthreads();
    }
    const int boffv = (blockIdx.x > 0) ? s[blockIdx.x - 1] : 0;  // exclusive
    const int total = s[255];
    if (blockIdx.x == 0 && t == 0) rowptr[n] = total;
    __syncthreads();

    const int base = blockIdx.x * 1024 + t * 4;
    int c[4] = {0, 0, 0, 0};
    if (base + 3 < n) {
        int4 c4 = *reinterpret_cast<const int4*>(cnt + base);
        c[0] = c4.x; c[1] = c4.y; c[2] = c4.z; c[3] = c4.w;
    } else {
        for (int i = 0; i < 4; ++i) if (base + i < n) c[i] = cnt[base + i];
    }
    const int tsum = c[0] + c[1] + c[2] + c[3];
    s[t] = tsum;
    __syncthreads();
    #pragma unroll
    for (int off = 1; off < 256; off <<= 1) {
        int v = (t >= off) ? s[t - off] : 0;
        __syncthreads();
        s[t] += v;
        __syncthreads();
    }
    int run = boffv + s[t] - tsum;
    int w0 = run;
    int w1 = run + c[0];
    int w2 = w1 + c[1];
    int w3 = w2 + c[2];
    if (base + 3 < n) {
        *reinterpret_cast<int4*>(rowptr + base) = make_int4(w0, w1, w2, w3);
    } else {
        int w[4] = {w0, w1, w2, w3};
        for (int i = 0; i < 4; ++i) if (base + i < n) rowptr[base + i] = w[i];
    }
}

// ===== fused_mid: scatter (atomic-free) || proj_q || proj_kv (pipelined) =====
// All three depend only on {fused_pre, scan_write2}; none feeds another.
// Scatter blocks are non-persistent and drain first; proj blocks are
// persistent grid-stride with R14's double-buffered LDS pipeline.
// Fusion-tax audit: envelope (VGPR ~proj, LDS 17.4 KB) costs scatter
// occupancy, but rank-scatter is streaming (no atomic latency chains).

__global__ __launch_bounds__(256) void fused_mid_kernel(
    const int* __restrict__ rows, const int* __restrict__ cols,
    const int* __restrict__ rank, const int* __restrict__ rowptr,
    int* __restrict__ colsorted, int nE, int n, int nbSc,
    const float* __restrict__ Xq, const float* __restrict__ Xm,
    const unsigned short* __restrict__ Fq, const float* __restrict__ bq,
    unsigned short* __restrict__ qout,
    const unsigned short* __restrict__ Fk, const float* __restrict__ bk,
    const unsigned short* __restrict__ Fv, const float* __restrict__ bv,
    unsigned char* __restrict__ kv, int m, int nTq, int nTm, int nbP)
{
    __shared__ __align__(16) unsigned short sX[2][32][136];
    const int bid = blockIdx.x;
    const int tid = threadIdx.x;

    if (bid < nbSc) {
        // ---- scatter: rank-based, 4 slices ----
        const int g  = bid & 3;
        const int lo = (int)(((long long)g * n) >> 2);
        const int hi = (int)(((long long)(g + 1) * n) >> 2);
        const int idx = (bid >> 2) * 2048 + tid * 8;
        if (idx + 7 < nE) {
            int4 ra = *reinterpret_cast<const int4*>(rows + idx);
            int4 rb = *reinterpret_cast<const int4*>(rows + idx + 4);
            int4 ca = *reinterpret_cast<const int4*>(cols + idx);
            int4 cb = *reinterpret_cast<const int4*>(cols + idx + 4);
            int4 ka = *reinterpret_cast<const int4*>(rank + idx);
            int4 kb = *reinterpret_cast<const int4*>(rank + idx + 4);
            int r[8] = {ra.x, ra.y, ra.z, ra.w, rb.x, rb.y, rb.z, rb.w};
            int c[8] = {ca.x, ca.y, ca.z, ca.w, cb.x, cb.y, cb.z, cb.w};
            int k[8] = {ka.x, ka.y, ka.z, ka.w, kb.x, kb.y, kb.z, kb.w};
            int p[8];
            #pragma unroll
            for (int j = 0; j < 8; ++j)
                p[j] = (r[j] >= lo && r[j] < hi) ? rowptr[r[j]] + k[j] : -1;
            #pragma unroll
            for (int j = 0; j < 8; ++j)
                if (p[j] >= 0) colsorted[p[j]] = c[j];
        } else {
            for (int i = 0; i < 8; ++i)
                if (idx + i < nE) {
                    int r = rows[idx + i];
                    if (r >= lo && r < hi)
                        colsorted[rowptr[r] + rank[idx + i]] = cols[idx + i];
                }
        }
        return;
    }

    // ---- projections: persistent, double-buffered 32-row tiles ----
    const int pb  = bid - nbSc;
    const bool isQ = pb < nbP;
    const float* X = isQ ? Xq : Xm;
    const int nn   = isQ ? n : m;
    const int nT   = isQ ? nTq : nTm;
    int tile       = isQ ? pb : pb - nbP;
    if (tile >= nT) return;

    const int l = tid & 63;
    const int ct = tid >> 6;           // wave w owns col-tile w
    const int arow = l & 31;
    const int col = ct * 32 + (l & 31);

    float4 r4[4];
    auto LOAD = [&](int t) {
        const int row0 = t * 32;
        #pragma unroll
        for (int p = 0; p < 4; ++p) {
            int flat = p * 256 + tid;
            int rr = flat >> 5;
            int cc = (flat & 31) * 4;
            int gr = row0 + rr; if (gr >= nn) gr = nn - 1;
            r4[p] = *reinterpret_cast<const float4*>(X + (size_t)gr * D + cc);
        }
    };
    auto STORE_LDS = [&](int buf) {
        #pragma unroll
        for (int p = 0; p < 4; ++p) {
            int flat = p * 256 + tid;
            int rr = flat >> 5;
            int cc = (flat & 31) * 4;
            uint2 pk;
            pk.x = (unsigned)f2bf(r4[p].x) | ((unsigned)f2bf(r4[p].y) << 16);
            pk.y = (unsigned)f2bf(r4[p].z) | ((unsigned)f2bf(r4[p].w) << 16);
            *reinterpret_cast<uint2*>(&sX[buf][rr][cc]) = pk;
        }
    };

    LOAD(tile);
    STORE_LDS(0);
    int cur = 0;
    const float bb1 = isQ ? bq[col] : bk[col];
    const float bb2 = isQ ? 0.0f : bv[col];

    while (tile < nT) {
        const int next = tile + nbP;
        __syncthreads();                       // sX[cur] ready; cross-buffer hazards fenced
        if (next < nT) LOAD(next);             // in flight during compute

        const int row0 = tile * 32;
        bf16x8 af[8];
        #pragma unroll
        for (int kt = 0; kt < 8; ++kt)
            af[kt] = *reinterpret_cast<const bf16x8*>(&sX[cur][arow][kt * 16 + (l >> 5) * 8]);

        if (isQ) {
            f32x16 acc = {};
            #pragma unroll
            for (int kt = 0; kt < 8; ++kt) {
                bf16x8 bfr = *reinterpret_cast<const bf16x8*>(Fq + ((size_t)((ct * 8 + kt) * 64 + l) * 8));
                acc = __builtin_amdgcn_mfma_f32_32x32x16_bf16(af[kt], bfr, acc, 0, 0, 0);
            }
            #pragma unroll
            for (int reg = 0; reg < 16; ++reg) {
                int rr = (reg & 3) + 8 * (reg >> 2) + 4 * (l >> 5);
                int gr = row0 + rr;
                if (gr < nn)
                    qout[(size_t)gr * D + col] = f2bf(gelu_fast(acc[reg] + bb1));
            }
        } else {
            #pragma unroll 1
            for (int mat = 0; mat < 2; ++mat) {
                const unsigned short* F = mat ? Fv : Fk;
                const float bb          = mat ? bb2 : bb1;
                f32x16 acc = {};
                #pragma unroll
                for (int kt = 0; kt < 8; ++kt) {
                    bf16x8 bfr = *reinterpret_cast<const bf16x8*>(F + ((size_t)((ct * 8 + kt) * 64 + l) * 8));
                    acc = __builtin_amdgcn_mfma_f32_32x32x16_bf16(af[kt], bfr, acc, 0, 0, 0);
                }
                #pragma unroll
                for (int reg = 0; reg < 16; ++reg) {
                    int rr = (reg & 3) + 8 * (reg >> 2) + 4 * (l >> 5);
                    int gr = row0 + rr;
                    if (gr < nn) {
                        unsigned char* rec = kv + (size_t)gr * KVREC;
                        float val = gelu_fast(acc[reg] + bb);
                        if (mat == 0)
                            rec[col] = f2fp8(val);
                        else
                            reinterpret_cast<unsigned short*>(rec + 128)[col] = f2bf(val);
                    }
                }
            }
        }

        if (next < nT) STORE_LDS(cur ^ 1);     // waits on LOAD(next) only here
        cur ^= 1;
        tile = next;
    }
}

// ===== aggregation: one wave/row, 4 edge slots x 16 dim lanes ================
// R15: colsorted prefetched 2 iterations ahead (cA/cB) so the column-index
// load is off the critical chain; only the kv gather latency stays exposed.
__global__ __launch_bounds__(256) void agg_kernel(
    const unsigned short* __restrict__ q, const unsigned char* __restrict__ kv,
    const int* __restrict__ rowptr, const int* __restrict__ colsorted,
    float* __restrict__ out, int n)
{
    const int wave = (blockIdx.x * 256 + threadIdx.x) >> 6;
    if (wave >= n) return;
    const int lane = threadIdx.x & 63;
    const int sub  = lane >> 4;
    const int l    = lane & 15;

    const uint4 qa = *reinterpret_cast<const uint4*>(q + (size_t)wave * D + l * 8);
    float qf[8];
    qf[0] = bflo(qa.x); qf[1] = bfhi(qa.x);
    qf[2] = bflo(qa.y); qf[3] = bfhi(qa.y);
    qf[4] = bflo(qa.z); qf[5] = bfhi(qa.z);
    qf[6] = bflo(qa.w); qf[7] = bfhi(qa.w);

    float acc[8] = {0.f,0.f,0.f,0.f,0.f,0.f,0.f,0.f};
    const int start = rowptr[wave], end = rowptr[wave + 1];

    int i  = start + sub;
    int cA = (i     < end) ? colsorted[i]     : 0;
    int cB = (i + 4 < end) ? colsorted[i + 4] : 0;

    #pragma unroll 2
    for (; i < end; i += 4) {
        const int c = cA;
        cA = cB;
        cB = (i + 8 < end) ? colsorted[i + 8] : 0;

        const unsigned char* rec = kv + (size_t)c * KVREC;
        const uint2 kb = *reinterpret_cast<const uint2*>(rec + l * 8);
        const uint4 vb = *reinterpret_cast<const uint4*>(rec + 128 + l * 16);

        float kf[8];
        fp8x4d(kb.x, kf); fp8x4d(kb.y, kf + 4);

        float dot = 0.0f;
        #pragma unroll
        for (int j = 0; j < 8; ++j) dot = fmaf(qf[j], kf[j], dot);
        dot += __shfl_xor(dot, 1);
        dot += __shfl_xor(dot, 2);
        dot += __shfl_xor(dot, 4);
        dot += __shfl_xor(dot, 8);
        const float coef = 1.0f / (1.0f + __expf(-dot * 0.08838834764831845f));

        acc[0] = fmaf(coef, bflo(vb.x), acc[0]);
        acc[1] = fmaf(coef, bfhi(vb.x), acc[1]);
        acc[2] = fmaf(coef, bflo(vb.y), acc[2]);
        acc[3] = fmaf(coef, bfhi(vb.y), acc[3]);
        acc[4] = fmaf(coef, bflo(vb.z), acc[4]);
        acc[5] = fmaf(coef, bfhi(vb.z), acc[5]);
        acc[6] = fmaf(coef, bflo(vb.w), acc[6]);
        acc[7] = fmaf(coef, bfhi(vb.w), acc[7]);
    }

    #pragma unroll
    for (int j = 0; j < 8; ++j) {
        acc[j] += __shfl_xor(acc[j], 16);
        acc[j] += __shfl_xor(acc[j], 32);
    }

    if (sub == 0) {
        float* op = out + (size_t)wave * D + l * 8;
        float4 o0 = {acc[0], acc[1], acc[2], acc[3]};
        float4 o1 = {acc[4], acc[5], acc[6], acc[7]};
        *reinterpret_cast<float4*>(op)     = o0;
        *reinterpret_cast<float4*>(op + 4) = o1;
    }
}

extern "C" void kernel_launch(void* const* d_in, const int* in_sizes, int n_in,
                              void* d_out, int out_size, void* d_ws, size_t ws_size,
                              hipStream_t stream) {
    const float* query  = (const float*)d_in[0];
    const float* memory = (const float*)d_in[1];
    const float* Wq     = (const float*)d_in[2];
    const float* bq     = (const float*)d_in[3];
    const float* Wk     = (const float*)d_in[4];
    const float* bk     = (const float*)d_in[5];
    const float* Wv     = (const float*)d_in[6];
    const float* bv     = (const float*)d_in[7];
    const int*   erows  = (const int*)d_in[8];
    const int*   ecols  = (const int*)d_in[9];

    const int n  = in_sizes[0] / D;   // 100000
    const int m  = in_sizes[1] / D;   // 100000
    const int nE = in_sizes[8];       // 1600000

    char* base = (char*)d_ws;
    size_t off = 0;
    auto carve = [&](size_t bytes) -> char* {
        char* p = base + off;
        off = (off + bytes + 255) & ~(size_t)255;
        return p;
    };
    unsigned short* q   = (unsigned short*)carve((size_t)n * D * sizeof(unsigned short));
    unsigned char*  kv  = (unsigned char*) carve((size_t)m * KVREC);
    unsigned short* F   = (unsigned short*)carve(3 * 32 * 64 * 8 * sizeof(unsigned short));
    int*   rowptr    = (int*)carve((size_t)(n + 1) * sizeof(int));
    int*   cnt       = (int*)carve((size_t)(n + 1) * sizeof(int));
    int*   rank      = (int*)carve((size_t)nE * sizeof(int));
    int*   bsum      = (int*)carve(256 * sizeof(int));
    int*   colsorted = (int*)carve((size_t)nE * sizeof(int));
    float* out       = (float*)d_out;

    unsigned short* Fq = F;
    unsigned short* Fk = F + 16384;
    unsigned short* Fv = F + 32768;

    dim3 blk(256);
    const int nbScan = (n + 1023) / 1024;            // 98 <= 256
    const int nbE8   = ((nE + 1023) / 1024) * 8;     // hist blocks (4 edges/thr, 8 slices)
    const int nbSc   = ((nE + 2047) / 2048) * 4;     // scatter blocks (8 edges/thr, 4 slices)
    const int nTq    = (n + 31) / 32;                // 32-row proj tiles
    const int nTm    = (m + 31) / 32;
    const int nbP    = 1024;                         // persistent proj blocks per matrix

    // 1) zero counters
    hipMemsetAsync(cnt, 0, (size_t)(n + 1) * sizeof(int), stream);
    // 2) hist(+rank) || prepack
    fused_pre_kernel<<<dim3(nbE8 + 192), blk, 0, stream>>>(
        erows, cnt, rank, nE, n, nbE8, Wq, Wk, Wv, F);
    // 3) block sums
    scan_bsum_kernel<<<dim3(nbScan), blk, 0, stream>>>(cnt, bsum, n);
    // 4) rowptr (inline boff re-scan)
    scan_write2_kernel<<<dim3(nbScan), blk, 0, stream>>>(cnt, bsum, nbScan, rowptr, n);
    // 5) scatter || proj_q || proj_kv (one dispatch; mutually independent)
    fused_mid_kernel<<<dim3(nbSc + 2 * nbP), blk, 0, stream>>>(
        erows, ecols, rank, rowptr, colsorted, nE, n, nbSc,
        query, memory, Fq, bq, q, Fk, bk, Fv, bv, kv, m, nTq, nTm, nbP);
    // 6) aggregation (writes all outputs; no out memset needed)
    agg_kernel<<<dim3((n * 64 + 255) / 256), blk, 0, stream>>>(q, kv, rowptr, colsorted, out, n);
}